// Round 3
// baseline (738.630 us; speedup 1.0000x reference)
//
#include <hip/hip_runtime.h>

// Problem constants: B=4, S=2048, D=1024, H=16, depth=64
#define SB 4
#define SS 2048
#define SD 1024
#define SH 16

typedef float f32x4 __attribute__((ext_vector_type(4)));
typedef __bf16 bf16x8 __attribute__((ext_vector_type(8)));
typedef short short4v __attribute__((ext_vector_type(4)));

__device__ __forceinline__ unsigned short f2bf_(float x) {
    unsigned u = __builtin_bit_cast(unsigned, x);
    unsigned r = u + 0x7FFFu + ((u >> 16) & 1u);
    return (unsigned short)(r >> 16);
}

#define GL2LDS(g, l) __builtin_amdgcn_global_load_lds( \
    (const __attribute__((address_space(1))) unsigned int*)(g), \
    (__attribute__((address_space(3))) unsigned int*)(l), 16, 0, 0)

// ---------------------------------------------------------------------------
// fp32 -> bf16 elementwise convert (vectorized float4 in, short4 out)
// ---------------------------------------------------------------------------
__global__ __launch_bounds__(256) void f2b_kernel(
        const float* __restrict__ in, unsigned short* __restrict__ out, int n) {
    int i = (blockIdx.x * 256 + threadIdx.x) * 4;
    int stride = gridDim.x * 256 * 4;
    for (; i < n; i += stride) {
        float4 v = *(const float4*)&in[i];
        short4v p;
        p[0] = (short)f2bf_(v.x); p[1] = (short)f2bf_(v.y);
        p[2] = (short)f2bf_(v.z); p[3] = (short)f2bf_(v.w);
        *(short4v*)&out[i] = p;
    }
}

// ---------------------------------------------------------------------------
// Transpose+convert 4 weight matrices fp32[1024,1024] -> bf16 [1024,1024]^T
// ---------------------------------------------------------------------------
__global__ __launch_bounds__(256) void transpose4(
        const float* __restrict__ w0, const float* __restrict__ w1,
        const float* __restrict__ w2, const float* __restrict__ w3,
        unsigned short* __restrict__ out) {
    __shared__ unsigned short tile[32][33];
    int zz = blockIdx.z;
    const float* src = (zz == 0) ? w0 : (zz == 1) ? w1 : (zz == 2) ? w2 : w3;
    unsigned short* dst = out + (size_t)zz * 1024 * 1024;
    int x = blockIdx.x * 32 + threadIdx.x;
    int y0 = blockIdx.y * 32;
    for (int j = threadIdx.y; j < 32; j += 8)
        tile[j][threadIdx.x] = f2bf_(src[(size_t)(y0 + j) * 1024 + x]);
    __syncthreads();
    int ox = y0 + threadIdx.x;
    int oy0 = blockIdx.x * 32;
    for (int j = threadIdx.y; j < 32; j += 8)
        dst[(size_t)(oy0 + j) * 1024 + ox] = tile[threadIdx.x][j];
}

// ---------------------------------------------------------------------------
// GEMM: C[M,N] = A[M,K] @ BT[N,K]^T + bias[N]  (A,BT bf16 bits; fp32 accum)
// STORE_MODE 0: C row-major [M,N] bf16
// STORE_MODE 1: V^T store: C[(b*1024 + n)*2048 + s], m = b*2048+s  (N==1024)
// STORE_MODE 2: C row-major [M,N] fp32
// 128x128 tile, BK=32, 256 threads (4 waves, 2x2), global_load_lds staging.
// ---------------------------------------------------------------------------
template <int STORE_MODE>
__global__ __launch_bounds__(256) void gemm_bt(
        const unsigned short* __restrict__ A, const unsigned short* __restrict__ BT,
        const float* __restrict__ bias, void* __restrict__ Cv,
        int M, int N, int K) {
    __shared__ alignas(16) unsigned short Asm[128][32];
    __shared__ alignas(16) unsigned short Bsm[128][32];
    const int m0 = blockIdx.y * 128, n0 = blockIdx.x * 128;
    const int tid = threadIdx.x;
    const int lane = tid & 63, wid = tid >> 6;
    const int wr = wid >> 1, wc = wid & 1;
    const int lr = lane >> 2;            // row within a 16-row staging chunk
    const int lco = (lane & 3) * 8;      // element offset (8 bf16 = 16B)

    f32x4 acc[4][4] = {};

    for (int k0 = 0; k0 < K; k0 += 32) {
#pragma unroll
        for (int it = 0; it < 2; ++it) {
            int rr = (it * 4 + wid) * 16;
            GL2LDS(A  + (size_t)(m0 + rr + lr) * K + k0 + lco, &Asm[rr][0]);
            GL2LDS(BT + (size_t)(n0 + rr + lr) * K + k0 + lco, &Bsm[rr][0]);
        }
        __syncthreads();
        bf16x8 af[4], bfv[4];
#pragma unroll
        for (int mi = 0; mi < 4; ++mi)
            af[mi] = *(const bf16x8*)&Asm[wr * 64 + mi * 16 + (lane & 15)][(lane >> 4) * 8];
#pragma unroll
        for (int ni = 0; ni < 4; ++ni)
            bfv[ni] = *(const bf16x8*)&Bsm[wc * 64 + ni * 16 + (lane & 15)][(lane >> 4) * 8];
#pragma unroll
        for (int mi = 0; mi < 4; ++mi)
#pragma unroll
            for (int ni = 0; ni < 4; ++ni)
                acc[mi][ni] = __builtin_amdgcn_mfma_f32_16x16x32_bf16(
                    af[mi], bfv[ni], acc[mi][ni], 0, 0, 0);
        __syncthreads();
    }

    const int cl = lane & 15, rl = (lane >> 4) * 4;
#pragma unroll
    for (int mi = 0; mi < 4; ++mi) {
#pragma unroll
        for (int ni = 0; ni < 4; ++ni) {
            int row = m0 + wr * 64 + mi * 16 + rl;
            int col = n0 + wc * 64 + ni * 16 + cl;
            float bv = bias[col];
            f32x4 v = acc[mi][ni];
            if (STORE_MODE == 0) {
                unsigned short* C = (unsigned short*)Cv;
#pragma unroll
                for (int j = 0; j < 4; ++j)
                    C[(size_t)(row + j) * N + col] = f2bf_(v[j] + bv);
            } else if (STORE_MODE == 1) {
                unsigned short* C = (unsigned short*)Cv;
                int bb = row >> 11, s = row & 2047;
                short4v pk;
#pragma unroll
                for (int j = 0; j < 4; ++j)
                    pk[j] = (short)f2bf_(v[j] + bv);
                *(short4v*)&C[((size_t)(bb * 1024 + col)) * 2048 + s] = pk;
            } else {
                float* C = (float*)Cv;
#pragma unroll
                for (int j = 0; j < 4; ++j)
                    C[(size_t)(row + j) * N + col] = v[j] + bv;
            }
        }
    }
}

// ---------------------------------------------------------------------------
// Flash attention. Qp,Kp: [B*S, 1024] bf16 (head h at cols h*64..). VT:
// [B*1024, 2048] bf16 (row = b*1024 + h*64 + d, col = s). mask: [B, S] int.
// Output O: [B*S, 1024] bf16 (concat heads).
// Block: 256 threads = 4 waves; wave owns 16 q-rows. KBLK=64.
// ---------------------------------------------------------------------------
__global__ __launch_bounds__(256) void attn_kernel(
        const unsigned short* __restrict__ Qp, const unsigned short* __restrict__ Kp,
        const unsigned short* __restrict__ VT, const int* __restrict__ mask,
        unsigned short* __restrict__ O) {
    __shared__ alignas(16) unsigned short P_lds[4][16][64];
    const int lane = threadIdx.x & 63, wid = threadIdx.x >> 6;
    const int qt = blockIdx.x, h = blockIdx.y, b = blockIdx.z;
    const int qrow0 = qt * 64 + wid * 16;
    const int cl = lane & 15, kg = lane >> 4;

    // Q fragments (A-operand): lane holds row cl, k = kh*32 + kg*8 .. +8
    bf16x8 qf[2];
#pragma unroll
    for (int kh = 0; kh < 2; ++kh)
        qf[kh] = *(const bf16x8*)&Qp[(size_t)(b * SS + qrow0 + cl) * SD + h * 64 + kh * 32 + kg * 8];

    f32x4 oacc[4] = {};
    float mrow[4] = {-1e30f, -1e30f, -1e30f, -1e30f};
    float lrow[4] = {0.f, 0.f, 0.f, 0.f};

    for (int kt = 0; kt < SS; kt += 64) {
        // ---- scores: S[16q x 64k] = Q @ K^T, 4 col-fragments x 2 k-halves
        f32x4 sfr[4];
#pragma unroll
        for (int cf = 0; cf < 4; ++cf) {
            f32x4 s = {};
#pragma unroll
            for (int kh = 0; kh < 2; ++kh) {
                bf16x8 kf = *(const bf16x8*)&Kp[(size_t)(b * SS + kt + cf * 16 + cl) * SD + h * 64 + kh * 32 + kg * 8];
                s = __builtin_amdgcn_mfma_f32_16x16x32_bf16(qf[kh], kf, s, 0, 0, 0);
            }
            sfr[cf] = s;
        }
        // ---- scale + mask (mask is per key position)
#pragma unroll
        for (int cf = 0; cf < 4; ++cf) {
            float madd = (float)mask[b * SS + kt + cf * 16 + cl] * -1e9f;
#pragma unroll
            for (int j = 0; j < 4; ++j)
                sfr[cf][j] = sfr[cf][j] * 0.125f + madd;
        }
        // ---- online softmax (each lane owns 4 q-rows: kg*4+j)
        float p[4][4];
#pragma unroll
        for (int j = 0; j < 4; ++j) {
            float rm = fmaxf(fmaxf(sfr[0][j], sfr[1][j]), fmaxf(sfr[2][j], sfr[3][j]));
            rm = fmaxf(rm, __shfl_xor(rm, 1));
            rm = fmaxf(rm, __shfl_xor(rm, 2));
            rm = fmaxf(rm, __shfl_xor(rm, 4));
            rm = fmaxf(rm, __shfl_xor(rm, 8));
            float nm = fmaxf(mrow[j], rm);
            float corr = __expf(mrow[j] - nm);
            float rs = 0.f;
#pragma unroll
            for (int cf = 0; cf < 4; ++cf) {
                float e = __expf(sfr[cf][j] - nm);
                p[cf][j] = e;
                rs += e;
            }
            rs += __shfl_xor(rs, 1);
            rs += __shfl_xor(rs, 2);
            rs += __shfl_xor(rs, 4);
            rs += __shfl_xor(rs, 8);
            lrow[j] = lrow[j] * corr + rs;
            mrow[j] = nm;
#pragma unroll
            for (int nf = 0; nf < 4; ++nf) oacc[nf][j] *= corr;
        }
        // ---- P -> LDS (re-fragment for PV A-operand)
        __syncthreads();  // prev iteration's P reads done before overwrite
#pragma unroll
        for (int cf = 0; cf < 4; ++cf)
#pragma unroll
            for (int j = 0; j < 4; ++j)
                P_lds[wid][kg * 4 + j][cf * 16 + cl] = f2bf_(p[cf][j]);
        __syncthreads();
        // ---- PV: O += P[16 x 64] @ V[64 x 64]
#pragma unroll
        for (int ks = 0; ks < 2; ++ks) {
            bf16x8 pf = *(const bf16x8*)&P_lds[wid][cl][ks * 32 + kg * 8];
#pragma unroll
            for (int nf = 0; nf < 4; ++nf) {
                bf16x8 vf = *(const bf16x8*)&VT[(size_t)(b * 1024 + h * 64 + nf * 16 + cl) * 2048 + kt + ks * 32 + kg * 8];
                oacc[nf] = __builtin_amdgcn_mfma_f32_16x16x32_bf16(pf, vf, oacc[nf], 0, 0, 0);
            }
        }
    }

    // ---- epilogue: O / l, store concat-head layout
#pragma unroll
    for (int j = 0; j < 4; ++j) {
        float inv = 1.0f / lrow[j];
#pragma unroll
        for (int nf = 0; nf < 4; ++nf)
            O[(size_t)(b * SS + qrow0 + kg * 4 + j) * SD + h * 64 + nf * 16 + cl] =
                f2bf_(oacc[nf][j] * inv);
    }
}

// ---------------------------------------------------------------------------
extern "C" void kernel_launch(void* const* d_in, const int* in_sizes, int n_in,
                              void* d_out, int out_size, void* d_ws, size_t ws_size,
                              hipStream_t stream) {
    const float* q  = (const float*)d_in[0];
    const float* k  = (const float*)d_in[1];
    const float* v  = (const float*)d_in[2];
    const int*   mk = (const int*)d_in[3];
    const float* wq = (const float*)d_in[4];
    const float* bq = (const float*)d_in[5];
    const float* wk = (const float*)d_in[6];
    const float* bk = (const float*)d_in[7];
    const float* wv = (const float*)d_in[8];
    const float* bv = (const float*)d_in[9];
    const float* wo = (const float*)d_in[10];
    const float* bo = (const float*)d_in[11];
    float* out = (float*)d_out;

    char* ws = (char*)d_ws;
    unsigned short* WT  = (unsigned short*)ws;                   // 4M bf16 = 8 MB
    unsigned short* X   = (unsigned short*)(ws + 8388608);       // 8.39M bf16 = 16 MB (reused)
    unsigned short* Qh  = (unsigned short*)(ws + 25165824);
    unsigned short* Kh  = (unsigned short*)(ws + 41943040);
    unsigned short* VTr = (unsigned short*)(ws + 58720256);
    // total 75,497,472 bytes

    const int NACT = SB * SS * SD;  // 8388608

    transpose4<<<dim3(32, 32, 4), dim3(32, 8), 0, stream>>>(wq, wk, wv, wo, WT);

    dim3 gg(8, 64), gb(256);
    dim3 cg(2048), cb(256);

    f2b_kernel<<<cg, cb, 0, stream>>>(q, X, NACT);
    gemm_bt<0><<<gg, gb, 0, stream>>>(X, WT,               bq, Qh,  8192, 1024, 1024);
    f2b_kernel<<<cg, cb, 0, stream>>>(k, X, NACT);
    gemm_bt<0><<<gg, gb, 0, stream>>>(X, WT + 1048576,     bk, Kh,  8192, 1024, 1024);
    f2b_kernel<<<cg, cb, 0, stream>>>(v, X, NACT);
    gemm_bt<1><<<gg, gb, 0, stream>>>(X, WT + 2 * 1048576, bv, VTr, 8192, 1024, 1024);

    attn_kernel<<<dim3(32, 16, 4), dim3(256), 0, stream>>>(Qh, Kh, VTr, mk, X);

    gemm_bt<2><<<gg, gb, 0, stream>>>(X, WT + 3 * 1048576, bo, out, 8192, 1024, 1024);
}

// Round 6
// 626.285 us; speedup vs baseline: 1.1794x; 1.1794x over previous
//
#include <hip/hip_runtime.h>

// Problem constants: B=4, S=2048, D=1024, H=16, depth=64
#define SB 4
#define SS 2048
#define SD 1024
#define SH 16

typedef float f32x4 __attribute__((ext_vector_type(4)));
typedef __bf16 bf16x8 __attribute__((ext_vector_type(8)));
typedef short short4v __attribute__((ext_vector_type(4)));

__device__ __forceinline__ unsigned short f2bf_(float x) {
    unsigned u = __builtin_bit_cast(unsigned, x);
    unsigned r = u + 0x7FFFu + ((u >> 16) & 1u);
    return (unsigned short)(r >> 16);
}

#define GL2LDS(g, l) __builtin_amdgcn_global_load_lds( \
    (const __attribute__((address_space(1))) unsigned int*)(g), \
    (__attribute__((address_space(3))) unsigned int*)(l), 16, 0, 0)

// ---- DPP 16-lane row reductions (quad_perm xor1, xor2, row_ror:4, row_ror:8)
template <int CTRL>
__device__ __forceinline__ float dppf_(float x) {
    return __builtin_bit_cast(float, __builtin_amdgcn_update_dpp(
        0, __builtin_bit_cast(int, x), CTRL, 0xF, 0xF, true));
}
__device__ __forceinline__ float rmax16_(float x) {
    x = fmaxf(x, dppf_<0xB1>(x));
    x = fmaxf(x, dppf_<0x4E>(x));
    x = fmaxf(x, dppf_<0x124>(x));
    x = fmaxf(x, dppf_<0x128>(x));
    return x;
}
__device__ __forceinline__ float rsum16_(float x) {
    x += dppf_<0xB1>(x);
    x += dppf_<0x4E>(x);
    x += dppf_<0x124>(x);
    x += dppf_<0x128>(x);
    return x;
}

// ---------------------------------------------------------------------------
// fp32 -> bf16 elementwise convert
// ---------------------------------------------------------------------------
__global__ __launch_bounds__(256) void f2b_kernel(
        const float* __restrict__ in, unsigned short* __restrict__ out, int n) {
    int i = (blockIdx.x * 256 + threadIdx.x) * 4;
    int stride = gridDim.x * 256 * 4;
    for (; i < n; i += stride) {
        float4 v = *(const float4*)&in[i];
        short4v p;
        p[0] = (short)f2bf_(v.x); p[1] = (short)f2bf_(v.y);
        p[2] = (short)f2bf_(v.z); p[3] = (short)f2bf_(v.w);
        *(short4v*)&out[i] = p;
    }
}

// ---------------------------------------------------------------------------
// Transpose+convert 4 weight matrices fp32[1024,1024] -> bf16 [1024,1024]^T
// ---------------------------------------------------------------------------
__global__ __launch_bounds__(256) void transpose4(
        const float* __restrict__ w0, const float* __restrict__ w1,
        const float* __restrict__ w2, const float* __restrict__ w3,
        unsigned short* __restrict__ out) {
    __shared__ unsigned short tile[32][33];
    int zz = blockIdx.z;
    const float* src = (zz == 0) ? w0 : (zz == 1) ? w1 : (zz == 2) ? w2 : w3;
    unsigned short* dst = out + (size_t)zz * 1024 * 1024;
    int x = blockIdx.x * 32 + threadIdx.x;
    int y0 = blockIdx.y * 32;
    for (int j = threadIdx.y; j < 32; j += 8)
        tile[j][threadIdx.x] = f2bf_(src[(size_t)(y0 + j) * 1024 + x]);
    __syncthreads();
    int ox = y0 + threadIdx.x;
    int oy0 = blockIdx.x * 32;
    for (int j = threadIdx.y; j < 32; j += 8)
        dst[(size_t)(oy0 + j) * 1024 + ox] = tile[threadIdx.x][j];
}

// ---------------------------------------------------------------------------
// GEMM: C[M,N] = A[M,K] @ BT[N,K]^T + bias[N]  (A,BT bf16 bits; fp32 accum)
// STORE_MODE 0: bf16 row-major; 1: V^T per-head store; 2: fp32 row-major
// ---------------------------------------------------------------------------
template <int STORE_MODE>
__global__ __launch_bounds__(256) void gemm_bt(
        const unsigned short* __restrict__ A, const unsigned short* __restrict__ BT,
        const float* __restrict__ bias, void* __restrict__ Cv,
        int M, int N, int K) {
    __shared__ alignas(16) unsigned short Asm[128][32];
    __shared__ alignas(16) unsigned short Bsm[128][32];
    const int m0 = blockIdx.y * 128, n0 = blockIdx.x * 128;
    const int tid = threadIdx.x;
    const int lane = tid & 63, wid = tid >> 6;
    const int wr = wid >> 1, wc = wid & 1;
    const int lr = lane >> 2;
    const int lco = (lane & 3) * 8;

    f32x4 acc[4][4] = {};

    for (int k0 = 0; k0 < K; k0 += 32) {
#pragma unroll
        for (int it = 0; it < 2; ++it) {
            int rr = (it * 4 + wid) * 16;
            GL2LDS(A  + (size_t)(m0 + rr + lr) * K + k0 + lco, &Asm[rr][0]);
            GL2LDS(BT + (size_t)(n0 + rr + lr) * K + k0 + lco, &Bsm[rr][0]);
        }
        __syncthreads();
        bf16x8 af[4], bfv[4];
#pragma unroll
        for (int mi = 0; mi < 4; ++mi)
            af[mi] = *(const bf16x8*)&Asm[wr * 64 + mi * 16 + (lane & 15)][(lane >> 4) * 8];
#pragma unroll
        for (int ni = 0; ni < 4; ++ni)
            bfv[ni] = *(const bf16x8*)&Bsm[wc * 64 + ni * 16 + (lane & 15)][(lane >> 4) * 8];
#pragma unroll
        for (int mi = 0; mi < 4; ++mi)
#pragma unroll
            for (int ni = 0; ni < 4; ++ni)
                acc[mi][ni] = __builtin_amdgcn_mfma_f32_16x16x32_bf16(
                    af[mi], bfv[ni], acc[mi][ni], 0, 0, 0);
        __syncthreads();
    }

    const int cl = lane & 15, rl = (lane >> 4) * 4;
#pragma unroll
    for (int mi = 0; mi < 4; ++mi) {
#pragma unroll
        for (int ni = 0; ni < 4; ++ni) {
            int row = m0 + wr * 64 + mi * 16 + rl;
            int col = n0 + wc * 64 + ni * 16 + cl;
            float bv = bias[col];
            f32x4 v = acc[mi][ni];
            if (STORE_MODE == 0) {
                unsigned short* C = (unsigned short*)Cv;
#pragma unroll
                for (int j = 0; j < 4; ++j)
                    C[(size_t)(row + j) * N + col] = f2bf_(v[j] + bv);
            } else if (STORE_MODE == 1) {
                unsigned short* C = (unsigned short*)Cv;
                int bb = row >> 11, s = row & 2047;
                short4v pk;
#pragma unroll
                for (int j = 0; j < 4; ++j)
                    pk[j] = (short)f2bf_(v[j] + bv);
                *(short4v*)&C[((size_t)(bb * 1024 + col)) * 2048 + s] = pk;
            } else {
                float* C = (float*)Cv;
#pragma unroll
                for (int j = 0; j < 4; ++j)
                    C[(size_t)(row + j) * N + col] = v[j] + bv;
            }
        }
    }
}

// ---------------------------------------------------------------------------
// Flash attention, latency-optimized:
//  - no __syncthreads (P_lds is per-wave)
//  - DPP row reductions (no DS-op shuffles)
//  - K double-buffered in regs one half-iter ahead; V/mask issued at iter start
//  - exp2-domain softmax
// Qp,Kp: [B*S,1024] bf16. VT: [B*1024,2048] bf16 (row=b*1024+h*64+d, col=s).
// mask: [B,S] int. O: [B*S,1024] bf16.
// ---------------------------------------------------------------------------
__global__ __launch_bounds__(256) void attn_kernel(
        const unsigned short* __restrict__ Qp, const unsigned short* __restrict__ Kp,
        const unsigned short* __restrict__ VT, const int* __restrict__ mask,
        unsigned short* __restrict__ O) {
    __shared__ alignas(16) unsigned short P_lds[4][16][72];  // padded rows (144B)
    const int lane = threadIdx.x & 63, wid = threadIdx.x >> 6;
    const int qt = blockIdx.x, h = blockIdx.y, b = blockIdx.z;
    const int qrow0 = qt * 64 + wid * 16;
    const int cl = lane & 15, kg = lane >> 4;

    const float SCL = 0.125f * 1.4426950408889634f;   // logits scale, log2 domain
    const float MSK = -1e9f * 1.4426950408889634f;

    // Q fragments (A-operand): lane holds row cl, k = kh*32 + kg*8 .. +8
    bf16x8 qf[2];
#pragma unroll
    for (int kh = 0; kh < 2; ++kh)
        qf[kh] = *(const bf16x8*)&Qp[(size_t)(b * SS + qrow0 + cl) * SD + h * 64 + kh * 32 + kg * 8];

    const unsigned short* Kb = Kp + ((size_t)(b * SS) + cl) * SD + h * 64 + kg * 8;
    const unsigned short* Vb = VT + ((size_t)(b * 1024 + h * 64 + cl)) * 2048 + kg * 8;
    const int* Mb = mask + b * SS + cl;

    f32x4 oacc[4] = {};
    float mrow[4] = {-1e30f, -1e30f, -1e30f, -1e30f};
    float lrow[4] = {0.f, 0.f, 0.f, 0.f};

    auto LOADK = [&](int kt, bf16x8* K) {
#pragma unroll
        for (int cf = 0; cf < 4; ++cf)
#pragma unroll
            for (int kh = 0; kh < 2; ++kh)
                K[cf * 2 + kh] = *(const bf16x8*)&Kb[(size_t)(kt + cf * 16) * SD + kh * 32];
    };
    auto LOADV = [&](int kt, bf16x8* V) {
#pragma unroll
        for (int ks = 0; ks < 2; ++ks)
#pragma unroll
            for (int nf = 0; nf < 4; ++nf)
                V[ks * 4 + nf] = *(const bf16x8*)&Vb[(size_t)(nf * 16) * 2048 + kt + ks * 32];
    };
    auto LOADM = [&](int kt, float* M) {
#pragma unroll
        for (int cf = 0; cf < 4; ++cf)
            M[cf] = (float)Mb[kt + cf * 16] * MSK;
    };

    auto STEP = [&](bf16x8* K, bf16x8* V, float* M) {
        // ---- scores (log2 domain)
        f32x4 sfr[4];
#pragma unroll
        for (int cf = 0; cf < 4; ++cf) {
            f32x4 s = {};
            s = __builtin_amdgcn_mfma_f32_16x16x32_bf16(qf[0], K[cf * 2 + 0], s, 0, 0, 0);
            s = __builtin_amdgcn_mfma_f32_16x16x32_bf16(qf[1], K[cf * 2 + 1], s, 0, 0, 0);
#pragma unroll
            for (int j = 0; j < 4; ++j)
                sfr[cf][j] = s[j] * SCL + M[cf];
        }
        // ---- online softmax; each lane owns 4 q-rows (kg*4+j); reduce over cl
#pragma unroll
        for (int j = 0; j < 4; ++j) {
            float rm = fmaxf(fmaxf(sfr[0][j], sfr[1][j]), fmaxf(sfr[2][j], sfr[3][j]));
            rm = rmax16_(rm);
            float nm = fmaxf(mrow[j], rm);
            float corr = __builtin_amdgcn_exp2f(mrow[j] - nm);
            float rs = 0.f;
#pragma unroll
            for (int cf = 0; cf < 4; ++cf) {
                float e = __builtin_amdgcn_exp2f(sfr[cf][j] - nm);
                P_lds[wid][kg * 4 + j][cf * 16 + cl] = f2bf_(e);
                rs += e;
            }
            rs = rsum16_(rs);
            lrow[j] = lrow[j] * corr + rs;
            mrow[j] = nm;
#pragma unroll
            for (int nf = 0; nf < 4; ++nf) oacc[nf][j] *= corr;
        }
        // ---- PV (within-wave LDS dependency; compiler inserts lgkmcnt waits)
#pragma unroll
        for (int ks = 0; ks < 2; ++ks) {
            bf16x8 pf = *(const bf16x8*)&P_lds[wid][cl][ks * 32 + kg * 8];
#pragma unroll
            for (int nf = 0; nf < 4; ++nf)
                oacc[nf] = __builtin_amdgcn_mfma_f32_16x16x32_bf16(pf, V[ks * 4 + nf], oacc[nf], 0, 0, 0);
        }
    };

    bf16x8 kA[8], kB[8], vC[8];
    float mC[4];
    LOADK(0, kA);
    for (int kt = 0; kt < SS; kt += 128) {
        LOADV(kt, vC);
        LOADM(kt, mC);
        LOADK(kt + 64, kB);                 // prefetch next half-iter's K
        STEP(kA, vC, mC);
        LOADV(kt + 64, vC);
        LOADM(kt + 64, mC);
        LOADK((kt + 128) & (SS - 1), kA);   // wraps harmlessly on last iter
        STEP(kB, vC, mC);
    }

    // ---- epilogue: O / l, store concat-head layout
#pragma unroll
    for (int j = 0; j < 4; ++j) {
        float inv = 1.0f / lrow[j];
#pragma unroll
        for (int nf = 0; nf < 4; ++nf)
            O[(size_t)(b * SS + qrow0 + kg * 4 + j) * SD + h * 64 + nf * 16 + cl] =
                f2bf_(oacc[nf][j] * inv);
    }
}

// ---------------------------------------------------------------------------
extern "C" void kernel_launch(void* const* d_in, const int* in_sizes, int n_in,
                              void* d_out, int out_size, void* d_ws, size_t ws_size,
                              hipStream_t stream) {
    const float* q  = (const float*)d_in[0];
    const float* k  = (const float*)d_in[1];
    const float* v  = (const float*)d_in[2];
    const int*   mk = (const int*)d_in[3];
    const float* wq = (const float*)d_in[4];
    const float* bq = (const float*)d_in[5];
    const float* wk = (const float*)d_in[6];
    const float* bk = (const float*)d_in[7];
    const float* wv = (const float*)d_in[8];
    const float* bv = (const float*)d_in[9];
    const float* wo = (const float*)d_in[10];
    const float* bo = (const float*)d_in[11];
    float* out = (float*)d_out;

    char* ws = (char*)d_ws;
    unsigned short* WT  = (unsigned short*)ws;                   // 8 MB
    unsigned short* X   = (unsigned short*)(ws + 8388608);       // 16 MB (reused)
    unsigned short* Qh  = (unsigned short*)(ws + 25165824);
    unsigned short* Kh  = (unsigned short*)(ws + 41943040);
    unsigned short* VTr = (unsigned short*)(ws + 58720256);

    const int NACT = SB * SS * SD;  // 8388608

    transpose4<<<dim3(32, 32, 4), dim3(32, 8), 0, stream>>>(wq, wk, wv, wo, WT);

    dim3 gg(8, 64), gb(256);
    dim3 cg(2048), cb(256);

    f2b_kernel<<<cg, cb, 0, stream>>>(q, X, NACT);
    gemm_bt<0><<<gg, gb, 0, stream>>>(X, WT,               bq, Qh,  8192, 1024, 1024);
    f2b_kernel<<<cg, cb, 0, stream>>>(k, X, NACT);
    gemm_bt<0><<<gg, gb, 0, stream>>>(X, WT + 1048576,     bk, Kh,  8192, 1024, 1024);
    f2b_kernel<<<cg, cb, 0, stream>>>(v, X, NACT);
    gemm_bt<1><<<gg, gb, 0, stream>>>(X, WT + 2 * 1048576, bv, VTr, 8192, 1024, 1024);

    attn_kernel<<<dim3(32, 16, 4), dim3(256), 0, stream>>>(Qh, Kh, VTr, mk, X);

    gemm_bt<2><<<gg, gb, 0, stream>>>(X, WT + 3 * 1048576, bo, out, 8192, 1024, 1024);
}

// Round 7
// 345.874 us; speedup vs baseline: 2.1355x; 1.8107x over previous
//
#include <hip/hip_runtime.h>

// Problem constants: B=4, S=2048, D=1024, H=16, depth=64
#define SB 4
#define SS 2048
#define SD 1024
#define SH 16

typedef float f32x4 __attribute__((ext_vector_type(4)));
typedef __bf16 bf16x8 __attribute__((ext_vector_type(8)));
typedef short short4v __attribute__((ext_vector_type(4)));

__device__ __forceinline__ unsigned short f2bf_(float x) {
    unsigned u = __builtin_bit_cast(unsigned, x);
    unsigned r = u + 0x7FFFu + ((u >> 16) & 1u);
    return (unsigned short)(r >> 16);
}

#define GL2LDS(g, l) __builtin_amdgcn_global_load_lds( \
    (const __attribute__((address_space(1))) unsigned int*)(g), \
    (__attribute__((address_space(3))) unsigned int*)(l), 16, 0, 0)

// ---- DPP 16-lane row reductions (quad_perm xor1, xor2, row_ror:4, row_ror:8)
template <int CTRL>
__device__ __forceinline__ float dppf_(float x) {
    return __builtin_bit_cast(float, __builtin_amdgcn_update_dpp(
        0, __builtin_bit_cast(int, x), CTRL, 0xF, 0xF, true));
}
__device__ __forceinline__ float rmax16_(float x) {
    x = fmaxf(x, dppf_<0xB1>(x));
    x = fmaxf(x, dppf_<0x4E>(x));
    x = fmaxf(x, dppf_<0x124>(x));
    x = fmaxf(x, dppf_<0x128>(x));
    return x;
}
__device__ __forceinline__ float rsum16_(float x) {
    x += dppf_<0xB1>(x);
    x += dppf_<0x4E>(x);
    x += dppf_<0x124>(x);
    x += dppf_<0x128>(x);
    return x;
}

// ---------------------------------------------------------------------------
// fp32 -> bf16 elementwise convert
// ---------------------------------------------------------------------------
__global__ __launch_bounds__(256) void f2b_kernel(
        const float* __restrict__ in, unsigned short* __restrict__ out, int n) {
    int i = (blockIdx.x * 256 + threadIdx.x) * 4;
    int stride = gridDim.x * 256 * 4;
    for (; i < n; i += stride) {
        float4 v = *(const float4*)&in[i];
        short4v p;
        p[0] = (short)f2bf_(v.x); p[1] = (short)f2bf_(v.y);
        p[2] = (short)f2bf_(v.z); p[3] = (short)f2bf_(v.w);
        *(short4v*)&out[i] = p;
    }
}

// ---------------------------------------------------------------------------
// Transpose+convert 4 weight matrices fp32[1024,1024] -> bf16 [1024,1024]^T
// ---------------------------------------------------------------------------
__global__ __launch_bounds__(256) void transpose4(
        const float* __restrict__ w0, const float* __restrict__ w1,
        const float* __restrict__ w2, const float* __restrict__ w3,
        unsigned short* __restrict__ out) {
    __shared__ unsigned short tile[32][33];
    int zz = blockIdx.z;
    const float* src = (zz == 0) ? w0 : (zz == 1) ? w1 : (zz == 2) ? w2 : w3;
    unsigned short* dst = out + (size_t)zz * 1024 * 1024;
    int x = blockIdx.x * 32 + threadIdx.x;
    int y0 = blockIdx.y * 32;
    for (int j = threadIdx.y; j < 32; j += 8)
        tile[j][threadIdx.x] = f2bf_(src[(size_t)(y0 + j) * 1024 + x]);
    __syncthreads();
    int ox = y0 + threadIdx.x;
    int oy0 = blockIdx.x * 32;
    for (int j = threadIdx.y; j < 32; j += 8)
        dst[(size_t)(oy0 + j) * 1024 + ox] = tile[threadIdx.x][j];
}

// ---------------------------------------------------------------------------
// GEMM: C[M,N] = A[M,K] @ BT[N,K]^T + bias[N]  (A,BT bf16 bits; fp32 accum)
// STORE_MODE 0: bf16 row-major; 1: V^T per-head store; 2: fp32 row-major
// ---------------------------------------------------------------------------
template <int STORE_MODE>
__global__ __launch_bounds__(256) void gemm_bt(
        const unsigned short* __restrict__ A, const unsigned short* __restrict__ BT,
        const float* __restrict__ bias, void* __restrict__ Cv,
        int M, int N, int K) {
    __shared__ alignas(16) unsigned short Asm[128][32];
    __shared__ alignas(16) unsigned short Bsm[128][32];
    const int m0 = blockIdx.y * 128, n0 = blockIdx.x * 128;
    const int tid = threadIdx.x;
    const int lane = tid & 63, wid = tid >> 6;
    const int wr = wid >> 1, wc = wid & 1;
    const int lr = lane >> 2;
    const int lco = (lane & 3) * 8;

    f32x4 acc[4][4] = {};

    for (int k0 = 0; k0 < K; k0 += 32) {
#pragma unroll
        for (int it = 0; it < 2; ++it) {
            int rr = (it * 4 + wid) * 16;
            GL2LDS(A  + (size_t)(m0 + rr + lr) * K + k0 + lco, &Asm[rr][0]);
            GL2LDS(BT + (size_t)(n0 + rr + lr) * K + k0 + lco, &Bsm[rr][0]);
        }
        __syncthreads();
        bf16x8 af[4], bfv[4];
#pragma unroll
        for (int mi = 0; mi < 4; ++mi)
            af[mi] = *(const bf16x8*)&Asm[wr * 64 + mi * 16 + (lane & 15)][(lane >> 4) * 8];
#pragma unroll
        for (int ni = 0; ni < 4; ++ni)
            bfv[ni] = *(const bf16x8*)&Bsm[wc * 64 + ni * 16 + (lane & 15)][(lane >> 4) * 8];
#pragma unroll
        for (int mi = 0; mi < 4; ++mi)
#pragma unroll
            for (int ni = 0; ni < 4; ++ni)
                acc[mi][ni] = __builtin_amdgcn_mfma_f32_16x16x32_bf16(
                    af[mi], bfv[ni], acc[mi][ni], 0, 0, 0);
        __syncthreads();
    }

    const int cl = lane & 15, rl = (lane >> 4) * 4;
#pragma unroll
    for (int mi = 0; mi < 4; ++mi) {
#pragma unroll
        for (int ni = 0; ni < 4; ++ni) {
            int row = m0 + wr * 64 + mi * 16 + rl;
            int col = n0 + wc * 64 + ni * 16 + cl;
            float bv = bias[col];
            f32x4 v = acc[mi][ni];
            if (STORE_MODE == 0) {
                unsigned short* C = (unsigned short*)Cv;
#pragma unroll
                for (int j = 0; j < 4; ++j)
                    C[(size_t)(row + j) * N + col] = f2bf_(v[j] + bv);
            } else if (STORE_MODE == 1) {
                unsigned short* C = (unsigned short*)Cv;
                int bb = row >> 11, s = row & 2047;
                short4v pk;
#pragma unroll
                for (int j = 0; j < 4; ++j)
                    pk[j] = (short)f2bf_(v[j] + bv);
                *(short4v*)&C[((size_t)(bb * 1024 + col)) * 2048 + s] = pk;
            } else {
                float* C = (float*)Cv;
#pragma unroll
                for (int j = 0; j < 4; ++j)
                    C[(size_t)(row + j) * N + col] = v[j] + bv;
            }
        }
    }
}

// ---------------------------------------------------------------------------
// Flash attention, LDS-staged K/V:
//  - K,V tiles (64x64 bf16 each) staged per-BLOCK via global_load_lds,
//    double-buffered; one barrier per tile; loads issued a full tile ahead
//  - T2 XOR swizzle (chunk ^= row&7) applied on the global SOURCE address
//    (gl2lds writes linearly) and re-applied on ds_read
//  - DPP row reductions, exp2-domain softmax, mask prefetched 1 tile ahead
// Qp,Kp: [B*S,1024] bf16. VT: [B*1024,2048] bf16 (row=b*1024+h*64+d, col=s).
// mask: [B,S] int. O: [B*S,1024] bf16.
// ---------------------------------------------------------------------------
__global__ __launch_bounds__(256) void attn_kernel(
        const unsigned short* __restrict__ Qp, const unsigned short* __restrict__ Kp,
        const unsigned short* __restrict__ VT, const int* __restrict__ mask,
        unsigned short* __restrict__ O) {
    __shared__ alignas(16) unsigned short Klds[2][64][64];
    __shared__ alignas(16) unsigned short Vlds[2][64][64];
    __shared__ alignas(16) unsigned short P_lds[4][16][72];
    const int lane = threadIdx.x & 63, wid = threadIdx.x >> 6;
    const int qt = blockIdx.x, h = blockIdx.y, b = blockIdx.z;
    const int qrow0 = qt * 64 + wid * 16;
    const int cl = lane & 15, kg = lane >> 4;
    const int sw = cl & 7;                  // read-side swizzle key (row&7)

    const float SCL = 0.125f * 1.4426950408889634f;   // log2-domain scale
    const float MSK = -1e9f * 1.4426950408889634f;

    // Q fragments (A-operand): lane holds row cl, k = kh*32 + kg*8 .. +8
    bf16x8 qf[2];
#pragma unroll
    for (int kh = 0; kh < 2; ++kh)
        qf[kh] = *(const bf16x8*)&Qp[(size_t)(b * SS + qrow0 + cl) * SD + h * 64 + kh * 32 + kg * 8];

    // staging geometry: per call, wave w covers 8 rows (lane/8), chunk = lane%8
    const int srow = (lane >> 3);           // row within wave's 8-row slab
    const int schk = (lane & 7);            // linear dest chunk (16B units)
    const int* Mb = mask + b * SS + cl;

    f32x4 oacc[4] = {};
    float mrow[4] = {-1e30f, -1e30f, -1e30f, -1e30f};
    float lrow[4] = {0.f, 0.f, 0.f, 0.f};

    auto STAGE = [&](int buf, int tt) {
        int kt = (tt & 31) * 64;
#pragma unroll
        for (int i = 0; i < 2; ++i) {
            int r = i * 32 + wid * 8 + srow;            // tile row 0..63
            int cs = schk ^ (r & 7);                    // pre-swizzled source chunk
            // K: row = key index, cols = head depth
            GL2LDS(Kp + (size_t)(b * SS + kt + r) * SD + h * 64 + cs * 8,
                   &Klds[buf][i * 32 + wid * 8][0]);
            // V: row = depth d, cols = key positions
            GL2LDS(VT + (size_t)(b * 1024 + h * 64 + r) * 2048 + kt + cs * 8,
                   &Vlds[buf][i * 32 + wid * 8][0]);
        }
    };

    auto STEP = [&](int buf, float* M) {
        // ---- scores (log2 domain): S[16q x 64k] = Q @ K^T
        f32x4 sfr[4];
#pragma unroll
        for (int cf = 0; cf < 4; ++cf) {
            int r = cf * 16 + cl;
            f32x4 s = {};
#pragma unroll
            for (int kh = 0; kh < 2; ++kh) {
                bf16x8 kf = *(const bf16x8*)&Klds[buf][r][((kh * 4 + kg) ^ sw) * 8];
                s = __builtin_amdgcn_mfma_f32_16x16x32_bf16(qf[kh], kf, s, 0, 0, 0);
            }
#pragma unroll
            for (int j = 0; j < 4; ++j)
                sfr[cf][j] = s[j] * SCL + M[cf];
        }
        // ---- online softmax; lane owns 4 q-rows (kg*4+j); reduce over cl
#pragma unroll
        for (int j = 0; j < 4; ++j) {
            float rm = fmaxf(fmaxf(sfr[0][j], sfr[1][j]), fmaxf(sfr[2][j], sfr[3][j]));
            rm = rmax16_(rm);
            float nm = fmaxf(mrow[j], rm);
            float corr = __builtin_amdgcn_exp2f(mrow[j] - nm);
            float rs = 0.f;
#pragma unroll
            for (int cf = 0; cf < 4; ++cf) {
                float e = __builtin_amdgcn_exp2f(sfr[cf][j] - nm);
                P_lds[wid][kg * 4 + j][cf * 16 + cl] = f2bf_(e);
                rs += e;
            }
            rs = rsum16_(rs);
            lrow[j] = lrow[j] * corr + rs;
            mrow[j] = nm;
#pragma unroll
            for (int nf = 0; nf < 4; ++nf) oacc[nf][j] *= corr;
        }
        // ---- PV: O += P[16 x 64] @ V[64 x 64]^T(d-major)
#pragma unroll
        for (int ks = 0; ks < 2; ++ks) {
            bf16x8 pf = *(const bf16x8*)&P_lds[wid][cl][ks * 32 + kg * 8];
#pragma unroll
            for (int nf = 0; nf < 4; ++nf) {
                int d = nf * 16 + cl;
                bf16x8 vf = *(const bf16x8*)&Vlds[buf][d][((ks * 4 + kg) ^ sw) * 8];
                oacc[nf] = __builtin_amdgcn_mfma_f32_16x16x32_bf16(pf, vf, oacc[nf], 0, 0, 0);
            }
        }
    };

    float mC[4], mN[4];
#pragma unroll
    for (int cf = 0; cf < 4; ++cf)
        mC[cf] = (float)Mb[cf * 16] * MSK;
    STAGE(0, 0);
    __syncthreads();

    for (int t = 0; t < 32; ++t) {
        int cur = t & 1;
        STAGE(cur ^ 1, t + 1);                       // async loads for next tile
        int ktn = ((t + 1) & 31) * 64;               // mask prefetch (regs)
#pragma unroll
        for (int cf = 0; cf < 4; ++cf)
            mN[cf] = (float)Mb[ktn + cf * 16] * MSK;
        STEP(cur, mC);
#pragma unroll
        for (int cf = 0; cf < 4; ++cf) mC[cf] = mN[cf];
        __syncthreads();                             // drains staging, orders bufs
    }

    // ---- epilogue: O / l, store concat-head layout
#pragma unroll
    for (int j = 0; j < 4; ++j) {
        float inv = 1.0f / lrow[j];
#pragma unroll
        for (int nf = 0; nf < 4; ++nf)
            O[(size_t)(b * SS + qrow0 + kg * 4 + j) * SD + h * 64 + nf * 16 + cl] =
                f2bf_(oacc[nf][j] * inv);
    }
}

// ---------------------------------------------------------------------------
extern "C" void kernel_launch(void* const* d_in, const int* in_sizes, int n_in,
                              void* d_out, int out_size, void* d_ws, size_t ws_size,
                              hipStream_t stream) {
    const float* q  = (const float*)d_in[0];
    const float* k  = (const float*)d_in[1];
    const float* v  = (const float*)d_in[2];
    const int*   mk = (const int*)d_in[3];
    const float* wq = (const float*)d_in[4];
    const float* bq = (const float*)d_in[5];
    const float* wk = (const float*)d_in[6];
    const float* bk = (const float*)d_in[7];
    const float* wv = (const float*)d_in[8];
    const float* bv = (const float*)d_in[9];
    const float* wo = (const float*)d_in[10];
    const float* bo = (const float*)d_in[11];
    float* out = (float*)d_out;

    char* ws = (char*)d_ws;
    unsigned short* WT  = (unsigned short*)ws;                   // 8 MB
    unsigned short* X   = (unsigned short*)(ws + 8388608);       // 16 MB (reused)
    unsigned short* Qh  = (unsigned short*)(ws + 25165824);
    unsigned short* Kh  = (unsigned short*)(ws + 41943040);
    unsigned short* VTr = (unsigned short*)(ws + 58720256);

    const int NACT = SB * SS * SD;  // 8388608

    transpose4<<<dim3(32, 32, 4), dim3(32, 8), 0, stream>>>(wq, wk, wv, wo, WT);

    dim3 gg(8, 64), gb(256);
    dim3 cg(2048), cb(256);

    f2b_kernel<<<cg, cb, 0, stream>>>(q, X, NACT);
    gemm_bt<0><<<gg, gb, 0, stream>>>(X, WT,               bq, Qh,  8192, 1024, 1024);
    f2b_kernel<<<cg, cb, 0, stream>>>(k, X, NACT);
    gemm_bt<0><<<gg, gb, 0, stream>>>(X, WT + 1048576,     bk, Kh,  8192, 1024, 1024);
    f2b_kernel<<<cg, cb, 0, stream>>>(v, X, NACT);
    gemm_bt<1><<<gg, gb, 0, stream>>>(X, WT + 2 * 1048576, bv, VTr, 8192, 1024, 1024);

    attn_kernel<<<dim3(32, 16, 4), dim3(256), 0, stream>>>(Qh, Kh, VTr, mk, X);

    gemm_bt<2><<<gg, gb, 0, stream>>>(X, WT + 3 * 1048576, bo, out, 8192, 1024, 1024);
}

// Round 8
// 331.356 us; speedup vs baseline: 2.2291x; 1.0438x over previous
//
#include <hip/hip_runtime.h>

// Problem constants: B=4, S=2048, D=1024, H=16, depth=64
#define SB 4
#define SS 2048
#define SD 1024
#define SH 16

typedef float f32x4 __attribute__((ext_vector_type(4)));
typedef __bf16 bf16x8 __attribute__((ext_vector_type(8)));
typedef short short4v __attribute__((ext_vector_type(4)));

__device__ __forceinline__ unsigned short f2bf_(float x) {
    unsigned u = __builtin_bit_cast(unsigned, x);
    unsigned r = u + 0x7FFFu + ((u >> 16) & 1u);
    return (unsigned short)(r >> 16);
}
// cheap round-half-up bf16 pack (P values are positive, well-scaled)
__device__ __forceinline__ unsigned short f2bf_r_(float x) {
    unsigned u = __builtin_bit_cast(unsigned, x);
    return (unsigned short)((u + 0x8000u) >> 16);
}

#define GL2LDS(g, l) __builtin_amdgcn_global_load_lds( \
    (const __attribute__((address_space(1))) unsigned int*)(g), \
    (__attribute__((address_space(3))) unsigned int*)(l), 16, 0, 0)

// ---- DPP 16-lane row reductions (quad_perm xor1, xor2, row_ror:4, row_ror:8)
template <int CTRL>
__device__ __forceinline__ float dppf_(float x) {
    return __builtin_bit_cast(float, __builtin_amdgcn_update_dpp(
        0, __builtin_bit_cast(int, x), CTRL, 0xF, 0xF, true));
}
__device__ __forceinline__ float rmax16_(float x) {
    x = fmaxf(x, dppf_<0xB1>(x));
    x = fmaxf(x, dppf_<0x4E>(x));
    x = fmaxf(x, dppf_<0x124>(x));
    x = fmaxf(x, dppf_<0x128>(x));
    return x;
}
__device__ __forceinline__ float rsum16_(float x) {
    x += dppf_<0xB1>(x);
    x += dppf_<0x4E>(x);
    x += dppf_<0x124>(x);
    x += dppf_<0x128>(x);
    return x;
}

// ---------------------------------------------------------------------------
// fp32 -> bf16 elementwise convert
// ---------------------------------------------------------------------------
__global__ __launch_bounds__(256) void f2b_kernel(
        const float* __restrict__ in, unsigned short* __restrict__ out, int n) {
    int i = (blockIdx.x * 256 + threadIdx.x) * 4;
    int stride = gridDim.x * 256 * 4;
    for (; i < n; i += stride) {
        float4 v = *(const float4*)&in[i];
        short4v p;
        p[0] = (short)f2bf_(v.x); p[1] = (short)f2bf_(v.y);
        p[2] = (short)f2bf_(v.z); p[3] = (short)f2bf_(v.w);
        *(short4v*)&out[i] = p;
    }
}

// ---------------------------------------------------------------------------
// Transpose+convert 4 weight matrices fp32[1024,1024] -> bf16 [1024,1024]^T
// ---------------------------------------------------------------------------
__global__ __launch_bounds__(256) void transpose4(
        const float* __restrict__ w0, const float* __restrict__ w1,
        const float* __restrict__ w2, const float* __restrict__ w3,
        unsigned short* __restrict__ out) {
    __shared__ unsigned short tile[32][33];
    int zz = blockIdx.z;
    const float* src = (zz == 0) ? w0 : (zz == 1) ? w1 : (zz == 2) ? w2 : w3;
    unsigned short* dst = out + (size_t)zz * 1024 * 1024;
    int x = blockIdx.x * 32 + threadIdx.x;
    int y0 = blockIdx.y * 32;
    for (int j = threadIdx.y; j < 32; j += 8)
        tile[j][threadIdx.x] = f2bf_(src[(size_t)(y0 + j) * 1024 + x]);
    __syncthreads();
    int ox = y0 + threadIdx.x;
    int oy0 = blockIdx.x * 32;
    for (int j = threadIdx.y; j < 32; j += 8)
        dst[(size_t)(oy0 + j) * 1024 + ox] = tile[threadIdx.x][j];
}

// ---------------------------------------------------------------------------
// GEMM: C[M,N] = (A[M,K] @ BT[N,K]^T + bias[N]) * oscale  (bf16 in, fp32 acc)
// STORE_MODE 0: bf16 row-major; 1: V^T per-head store; 2: fp32 row-major
// ---------------------------------------------------------------------------
template <int STORE_MODE>
__global__ __launch_bounds__(256) void gemm_bt(
        const unsigned short* __restrict__ A, const unsigned short* __restrict__ BT,
        const float* __restrict__ bias, void* __restrict__ Cv,
        int M, int N, int K, float oscale) {
    __shared__ alignas(16) unsigned short Asm[128][32];
    __shared__ alignas(16) unsigned short Bsm[128][32];
    const int m0 = blockIdx.y * 128, n0 = blockIdx.x * 128;
    const int tid = threadIdx.x;
    const int lane = tid & 63, wid = tid >> 6;
    const int wr = wid >> 1, wc = wid & 1;
    const int lr = lane >> 2;
    const int lco = (lane & 3) * 8;

    f32x4 acc[4][4] = {};

    for (int k0 = 0; k0 < K; k0 += 32) {
#pragma unroll
        for (int it = 0; it < 2; ++it) {
            int rr = (it * 4 + wid) * 16;
            GL2LDS(A  + (size_t)(m0 + rr + lr) * K + k0 + lco, &Asm[rr][0]);
            GL2LDS(BT + (size_t)(n0 + rr + lr) * K + k0 + lco, &Bsm[rr][0]);
        }
        __syncthreads();
        bf16x8 af[4], bfv[4];
#pragma unroll
        for (int mi = 0; mi < 4; ++mi)
            af[mi] = *(const bf16x8*)&Asm[wr * 64 + mi * 16 + (lane & 15)][(lane >> 4) * 8];
#pragma unroll
        for (int ni = 0; ni < 4; ++ni)
            bfv[ni] = *(const bf16x8*)&Bsm[wc * 64 + ni * 16 + (lane & 15)][(lane >> 4) * 8];
#pragma unroll
        for (int mi = 0; mi < 4; ++mi)
#pragma unroll
            for (int ni = 0; ni < 4; ++ni)
                acc[mi][ni] = __builtin_amdgcn_mfma_f32_16x16x32_bf16(
                    af[mi], bfv[ni], acc[mi][ni], 0, 0, 0);
        __syncthreads();
    }

    const int cl = lane & 15, rl = (lane >> 4) * 4;
#pragma unroll
    for (int mi = 0; mi < 4; ++mi) {
#pragma unroll
        for (int ni = 0; ni < 4; ++ni) {
            int row = m0 + wr * 64 + mi * 16 + rl;
            int col = n0 + wc * 64 + ni * 16 + cl;
            float bv = bias[col];
            f32x4 v = acc[mi][ni];
            if (STORE_MODE == 0) {
                unsigned short* C = (unsigned short*)Cv;
#pragma unroll
                for (int j = 0; j < 4; ++j)
                    C[(size_t)(row + j) * N + col] = f2bf_((v[j] + bv) * oscale);
            } else if (STORE_MODE == 1) {
                unsigned short* C = (unsigned short*)Cv;
                int bb = row >> 11, s = row & 2047;
                short4v pk;
#pragma unroll
                for (int j = 0; j < 4; ++j)
                    pk[j] = (short)f2bf_(v[j] + bv);
                *(short4v*)&C[((size_t)(bb * 1024 + col)) * 2048 + s] = pk;
            } else {
                float* C = (float*)Cv;
#pragma unroll
                for (int j = 0; j < 4; ++j)
                    C[(size_t)(row + j) * N + col] = v[j] + bv;
            }
        }
    }
}

// ---------------------------------------------------------------------------
// Flash attention, KBLK=128, LDS-staged K/V (double-buffered, XOR-swizzled),
// one softmax pass per 128 keys, defer-max rescale (THR=8, log2 domain).
// Qp: [B*S,1024] bf16 (PRE-SCALED by 0.125*log2e). Kp: [B*S,1024] bf16.
// VT: [B*1024,2048] bf16 (row=b*1024+h*64+d, col=s). mask: [B,S] int.
// O: [B*S,1024] bf16.
// ---------------------------------------------------------------------------
__global__ __launch_bounds__(256) void attn_kernel(
        const unsigned short* __restrict__ Qp, const unsigned short* __restrict__ Kp,
        const unsigned short* __restrict__ VT, const int* __restrict__ mask,
        unsigned short* __restrict__ O) {
    __shared__ alignas(16) unsigned short Klds[2][128][64];
    __shared__ alignas(16) unsigned short Vlds[2][64][128];
    __shared__ alignas(16) unsigned short P_lds[4][16][72];
    const int lane = threadIdx.x & 63, wid = threadIdx.x >> 6;
    const int qt = blockIdx.x, h = blockIdx.y, b = blockIdx.z;
    const int qrow0 = qt * 64 + wid * 16;
    const int cl = lane & 15, kg = lane >> 4;

    const float MSK = -1e9f * 1.4426950408889634f;   // mask add, log2 domain
    const float THR = 8.0f;                           // defer-max threshold

    // Q fragments (A-operand): lane holds row cl, k = kh*32 + kg*8 .. +8
    bf16x8 qf[2];
#pragma unroll
    for (int kh = 0; kh < 2; ++kh)
        qf[kh] = *(const bf16x8*)&Qp[(size_t)(b * SS + qrow0 + cl) * SD + h * 64 + kh * 32 + kg * 8];

    const int* Mb = mask + b * SS + cl;

    f32x4 oacc[4] = {};
    float mrow[4] = {-1e30f, -1e30f, -1e30f, -1e30f};
    float lrow[4] = {0.f, 0.f, 0.f, 0.f};

    auto STAGE = [&](int buf, int tt) {
        int kt = (tt & 15) * 128;
        // K tile: 128 rows x 64 cols; wave covers 8 rows per pass
        {
            int r8 = lane >> 3, c8 = lane & 7;
#pragma unroll
            for (int i = 0; i < 4; ++i) {
                int r = i * 32 + wid * 8 + r8;
                int cs = c8 ^ (r & 7);
                GL2LDS(Kp + (size_t)(b * SS + kt + r) * SD + h * 64 + cs * 8,
                       &Klds[buf][i * 32 + wid * 8][0]);
            }
        }
        // V tile: 64 rows x 128 cols; wave covers 4 rows per pass
        {
            int r16 = lane >> 4, c16 = lane & 15;
#pragma unroll
            for (int i = 0; i < 4; ++i) {
                int r = i * 16 + wid * 4 + r16;
                int cs = (c16 & 8) | ((c16 & 7) ^ (r & 7));
                GL2LDS(VT + (size_t)(b * 1024 + h * 64 + r) * 2048 + kt + cs * 8,
                       &Vlds[buf][i * 16 + wid * 4][0]);
            }
        }
    };

    auto STEP = [&](int buf, float* M) {
        // ---- scores (log2 domain, scale pre-folded into Q)
        f32x4 sfr[8];
#pragma unroll
        for (int cf = 0; cf < 8; ++cf) {
            int r = cf * 16 + cl;
            f32x4 s = {};
#pragma unroll
            for (int kh = 0; kh < 2; ++kh) {
                bf16x8 kf = *(const bf16x8*)&Klds[buf][r][((kh * 4 + kg) ^ (r & 7)) * 8];
                s = __builtin_amdgcn_mfma_f32_16x16x32_bf16(qf[kh], kf, s, 0, 0, 0);
            }
#pragma unroll
            for (int j = 0; j < 4; ++j)
                sfr[cf][j] = s[j] + M[cf];
        }
        // ---- row maxima (lane owns 4 q-rows kg*4+j; reduce over 16 cl lanes)
        float rm[4];
#pragma unroll
        for (int j = 0; j < 4; ++j) {
            float a = fmaxf(fmaxf(fmaxf(sfr[0][j], sfr[1][j]), fmaxf(sfr[2][j], sfr[3][j])),
                            fmaxf(fmaxf(sfr[4][j], sfr[5][j]), fmaxf(sfr[6][j], sfr[7][j])));
            rm[j] = rmax16_(a);
        }
        // ---- defer-max: rescale only if some row grew past THR
        bool need = (rm[0] > mrow[0] + THR) | (rm[1] > mrow[1] + THR) |
                    (rm[2] > mrow[2] + THR) | (rm[3] > mrow[3] + THR);
        if (__any(need)) {
#pragma unroll
            for (int j = 0; j < 4; ++j) {
                float nm = fmaxf(mrow[j], rm[j]);
                float corr = __builtin_amdgcn_exp2f(mrow[j] - nm);
                mrow[j] = nm;
                lrow[j] *= corr;
#pragma unroll
                for (int nf = 0; nf < 4; ++nf) oacc[nf][j] *= corr;
            }
        }
        // ---- exponentials (bounded by 2^THR) + row sums
#pragma unroll
        for (int cf = 0; cf < 8; ++cf)
#pragma unroll
            for (int j = 0; j < 4; ++j)
                sfr[cf][j] = __builtin_amdgcn_exp2f(sfr[cf][j] - mrow[j]);
#pragma unroll
        for (int j = 0; j < 4; ++j) {
            float rs = (sfr[0][j] + sfr[1][j]) + (sfr[2][j] + sfr[3][j]) +
                       (sfr[4][j] + sfr[5][j]) + (sfr[6][j] + sfr[7][j]);
            lrow[j] += rsum16_(rs);
        }
        // ---- PV in two 64-key halves (per-wave P_lds reuse; DS in-order)
#pragma unroll
        for (int h2 = 0; h2 < 2; ++h2) {
#pragma unroll
            for (int cf = 0; cf < 4; ++cf)
#pragma unroll
                for (int j = 0; j < 4; ++j)
                    P_lds[wid][kg * 4 + j][cf * 16 + cl] = f2bf_r_(sfr[h2 * 4 + cf][j]);
#pragma unroll
            for (int ks = 0; ks < 2; ++ks) {
                bf16x8 pf = *(const bf16x8*)&P_lds[wid][cl][ks * 32 + kg * 8];
#pragma unroll
                for (int nf = 0; nf < 4; ++nf) {
                    int d = nf * 16 + cl;
                    int c = h2 * 8 + ks * 4 + kg;
                    bf16x8 vf = *(const bf16x8*)&Vlds[buf][d][((c & 8) | ((c & 7) ^ (d & 7))) * 8];
                    oacc[nf] = __builtin_amdgcn_mfma_f32_16x16x32_bf16(pf, vf, oacc[nf], 0, 0, 0);
                }
            }
        }
    };

    float mC[8], mN[8];
#pragma unroll
    for (int cf = 0; cf < 8; ++cf)
        mC[cf] = (float)Mb[cf * 16] * MSK;
    STAGE(0, 0);
    __syncthreads();

    for (int t = 0; t < 16; ++t) {
        int cur = t & 1;
        STAGE(cur ^ 1, t + 1);                       // async loads for next tile
        int ktn = ((t + 1) & 15) * 128;              // mask prefetch (regs)
#pragma unroll
        for (int cf = 0; cf < 8; ++cf)
            mN[cf] = (float)Mb[ktn + cf * 16] * MSK;
        STEP(cur, mC);
#pragma unroll
        for (int cf = 0; cf < 8; ++cf) mC[cf] = mN[cf];
        __syncthreads();                             // drains staging, orders bufs
    }

    // ---- epilogue: O / l, store concat-head layout
#pragma unroll
    for (int j = 0; j < 4; ++j) {
        float inv = 1.0f / lrow[j];
#pragma unroll
        for (int nf = 0; nf < 4; ++nf)
            O[(size_t)(b * SS + qrow0 + kg * 4 + j) * SD + h * 64 + nf * 16 + cl] =
                f2bf_(oacc[nf][j] * inv);
    }
}

// ---------------------------------------------------------------------------
extern "C" void kernel_launch(void* const* d_in, const int* in_sizes, int n_in,
                              void* d_out, int out_size, void* d_ws, size_t ws_size,
                              hipStream_t stream) {
    const float* q  = (const float*)d_in[0];
    const float* k  = (const float*)d_in[1];
    const float* v  = (const float*)d_in[2];
    const int*   mk = (const int*)d_in[3];
    const float* wq = (const float*)d_in[4];
    const float* bq = (const float*)d_in[5];
    const float* wk = (const float*)d_in[6];
    const float* bk = (const float*)d_in[7];
    const float* wv = (const float*)d_in[8];
    const float* bv = (const float*)d_in[9];
    const float* wo = (const float*)d_in[10];
    const float* bo = (const float*)d_in[11];
    float* out = (float*)d_out;

    char* ws = (char*)d_ws;
    unsigned short* WT  = (unsigned short*)ws;                   // 8 MB
    unsigned short* X   = (unsigned short*)(ws + 8388608);       // 16 MB (reused)
    unsigned short* Qh  = (unsigned short*)(ws + 25165824);
    unsigned short* Kh  = (unsigned short*)(ws + 41943040);
    unsigned short* VTr = (unsigned short*)(ws + 58720256);

    const int NACT = SB * SS * SD;  // 8388608
    const float QSCL = 0.125f * 1.4426950408889634f;  // 1/sqrt(64) * log2(e)

    transpose4<<<dim3(32, 32, 4), dim3(32, 8), 0, stream>>>(wq, wk, wv, wo, WT);

    dim3 gg(8, 64), gb(256);
    dim3 cg(2048), cb(256);

    f2b_kernel<<<cg, cb, 0, stream>>>(q, X, NACT);
    gemm_bt<0><<<gg, gb, 0, stream>>>(X, WT,               bq, Qh,  8192, 1024, 1024, QSCL);
    f2b_kernel<<<cg, cb, 0, stream>>>(k, X, NACT);
    gemm_bt<0><<<gg, gb, 0, stream>>>(X, WT + 1048576,     bk, Kh,  8192, 1024, 1024, 1.0f);
    f2b_kernel<<<cg, cb, 0, stream>>>(v, X, NACT);
    gemm_bt<1><<<gg, gb, 0, stream>>>(X, WT + 2 * 1048576, bv, VTr, 8192, 1024, 1024, 1.0f);

    attn_kernel<<<dim3(32, 16, 4), dim3(256), 0, stream>>>(Qh, Kh, VTr, mk, X);

    gemm_bt<2><<<gg, gb, 0, stream>>>(X, WT + 3 * 1048576, bo, out, 8192, 1024, 1024, 1.0f);
}

// Round 9
// 264.833 us; speedup vs baseline: 2.7890x; 1.2512x over previous
//
#include <hip/hip_runtime.h>

// Problem constants: B=4, S=2048, D=1024, H=16, depth=64
#define SB 4
#define SS 2048
#define SD 1024
#define SH 16

typedef float f32x4 __attribute__((ext_vector_type(4)));
typedef __bf16 bf16x8 __attribute__((ext_vector_type(8)));
typedef short short4v __attribute__((ext_vector_type(4)));
typedef unsigned int uint2v __attribute__((ext_vector_type(2)));

__device__ __forceinline__ unsigned short f2bf_(float x) {
    unsigned u = __builtin_bit_cast(unsigned, x);
    unsigned r = u + 0x7FFFu + ((u >> 16) & 1u);
    return (unsigned short)(r >> 16);
}

#define GL2LDS(g, l) __builtin_amdgcn_global_load_lds( \
    (const __attribute__((address_space(1))) unsigned int*)(g), \
    (__attribute__((address_space(3))) unsigned int*)(l), 16, 0, 0)

// ---------------------------------------------------------------------------
// fp32 -> bf16 elementwise convert
// ---------------------------------------------------------------------------
__global__ __launch_bounds__(256) void f2b_kernel(
        const float* __restrict__ in, unsigned short* __restrict__ out, int n) {
    int i = (blockIdx.x * 256 + threadIdx.x) * 4;
    int stride = gridDim.x * 256 * 4;
    for (; i < n; i += stride) {
        float4 v = *(const float4*)&in[i];
        short4v p;
        p[0] = (short)f2bf_(v.x); p[1] = (short)f2bf_(v.y);
        p[2] = (short)f2bf_(v.z); p[3] = (short)f2bf_(v.w);
        *(short4v*)&out[i] = p;
    }
}

// ---------------------------------------------------------------------------
// Transpose+convert 4 weight matrices fp32[1024,1024] -> bf16 [1024,1024]^T
// ---------------------------------------------------------------------------
__global__ __launch_bounds__(256) void transpose4(
        const float* __restrict__ w0, const float* __restrict__ w1,
        const float* __restrict__ w2, const float* __restrict__ w3,
        unsigned short* __restrict__ out) {
    __shared__ unsigned short tile[32][33];
    int zz = blockIdx.z;
    const float* src = (zz == 0) ? w0 : (zz == 1) ? w1 : (zz == 2) ? w2 : w3;
    unsigned short* dst = out + (size_t)zz * 1024 * 1024;
    int x = blockIdx.x * 32 + threadIdx.x;
    int y0 = blockIdx.y * 32;
    for (int j = threadIdx.y; j < 32; j += 8)
        tile[j][threadIdx.x] = f2bf_(src[(size_t)(y0 + j) * 1024 + x]);
    __syncthreads();
    int ox = y0 + threadIdx.x;
    int oy0 = blockIdx.x * 32;
    for (int j = threadIdx.y; j < 32; j += 8)
        dst[(size_t)(oy0 + j) * 1024 + ox] = tile[threadIdx.x][j];
}

// ---------------------------------------------------------------------------
// GEMM: C[M,N] = (A[M,K] @ BT[N,K]^T + bias[N]) * oscale  (bf16 in, fp32 acc)
// STORE_MODE 0: bf16 row-major; 1: V^T per-head store; 2: fp32 row-major
// ---------------------------------------------------------------------------
template <int STORE_MODE>
__global__ __launch_bounds__(256) void gemm_bt(
        const unsigned short* __restrict__ A, const unsigned short* __restrict__ BT,
        const float* __restrict__ bias, void* __restrict__ Cv,
        int M, int N, int K, float oscale) {
    __shared__ alignas(16) unsigned short Asm[128][32];
    __shared__ alignas(16) unsigned short Bsm[128][32];
    const int m0 = blockIdx.y * 128, n0 = blockIdx.x * 128;
    const int tid = threadIdx.x;
    const int lane = tid & 63, wid = tid >> 6;
    const int wr = wid >> 1, wc = wid & 1;
    const int lr = lane >> 2;
    const int lco = (lane & 3) * 8;

    f32x4 acc[4][4] = {};

    for (int k0 = 0; k0 < K; k0 += 32) {
#pragma unroll
        for (int it = 0; it < 2; ++it) {
            int rr = (it * 4 + wid) * 16;
            GL2LDS(A  + (size_t)(m0 + rr + lr) * K + k0 + lco, &Asm[rr][0]);
            GL2LDS(BT + (size_t)(n0 + rr + lr) * K + k0 + lco, &Bsm[rr][0]);
        }
        __syncthreads();
        bf16x8 af[4], bfv[4];
#pragma unroll
        for (int mi = 0; mi < 4; ++mi)
            af[mi] = *(const bf16x8*)&Asm[wr * 64 + mi * 16 + (lane & 15)][(lane >> 4) * 8];
#pragma unroll
        for (int ni = 0; ni < 4; ++ni)
            bfv[ni] = *(const bf16x8*)&Bsm[wc * 64 + ni * 16 + (lane & 15)][(lane >> 4) * 8];
#pragma unroll
        for (int mi = 0; mi < 4; ++mi)
#pragma unroll
            for (int ni = 0; ni < 4; ++ni)
                acc[mi][ni] = __builtin_amdgcn_mfma_f32_16x16x32_bf16(
                    af[mi], bfv[ni], acc[mi][ni], 0, 0, 0);
        __syncthreads();
    }

    const int cl = lane & 15, rl = (lane >> 4) * 4;
#pragma unroll
    for (int mi = 0; mi < 4; ++mi) {
#pragma unroll
        for (int ni = 0; ni < 4; ++ni) {
            int row = m0 + wr * 64 + mi * 16 + rl;
            int col = n0 + wc * 64 + ni * 16 + cl;
            float bv = bias[col];
            f32x4 v = acc[mi][ni];
            if (STORE_MODE == 0) {
                unsigned short* C = (unsigned short*)Cv;
#pragma unroll
                for (int j = 0; j < 4; ++j)
                    C[(size_t)(row + j) * N + col] = f2bf_((v[j] + bv) * oscale);
            } else if (STORE_MODE == 1) {
                unsigned short* C = (unsigned short*)Cv;
                int bb = row >> 11, s = row & 2047;
                short4v pk;
#pragma unroll
                for (int j = 0; j < 4; ++j)
                    pk[j] = (short)f2bf_(v[j] + bv);
                *(short4v*)&C[((size_t)(bb * 1024 + col)) * 2048 + s] = pk;
            } else {
                float* C = (float*)Cv;
#pragma unroll
                for (int j = 0; j < 4; ++j)
                    C[(size_t)(row + j) * N + col] = v[j] + bv;
            }
        }
    }
}

// ---------------------------------------------------------------------------
// Flash attention v3: swapped QK^T (P register-resident), fixed-max softmax
// (m = 8 in log2 domain; logits provably bounded), 32 q-rows per wave,
// KBLK=128 LDS-staged K/V (double-buffered, XOR-swizzled source staging).
// Qp: [B*S,1024] bf16 PRE-SCALED by 0.125*log2e. Kp: [B*S,1024] bf16.
// VT: [B*1024,2048] bf16 (row=b*1024+h*64+d, col=s). mask: [B,S] int.
// O: [B*S,1024] bf16. Grid: (x = b*16+h, y = qt) so q-tiles of one (b,h)
// share an XCD (linear-id % 8 invariant in y).
// ---------------------------------------------------------------------------
__global__ __launch_bounds__(256, 2) void attn_kernel(
        const unsigned short* __restrict__ Qp, const unsigned short* __restrict__ Kp,
        const unsigned short* __restrict__ VT, const int* __restrict__ mask,
        unsigned short* __restrict__ O) {
    __shared__ alignas(16) unsigned short Klds[2][128][64];
    __shared__ alignas(16) unsigned short Vlds[2][64][128];
    const int lane = threadIdx.x & 63, wid = threadIdx.x >> 6;
    const int bh = blockIdx.x;
    const int b = bh >> 4, h = bh & 15;
    const int qt = blockIdx.y;
    const int qrow0 = qt * 128 + wid * 32;
    const int cl = lane & 15, kg = lane >> 4;

    const float MSK = -1e9f * 1.4426950408889634f;

    // Q as B-operand: frag [qh][kh]: col=cl -> q=qrow0+qh*16+cl, k=kh*32+kg*8
    bf16x8 qf[2][2];
#pragma unroll
    for (int qh = 0; qh < 2; ++qh)
#pragma unroll
        for (int kh = 0; kh < 2; ++kh)
            qf[qh][kh] = *(const bf16x8*)&Qp[(size_t)(b * SS + qrow0 + qh * 16 + cl) * SD
                                            + h * 64 + kh * 32 + kg * 8];

    const int* Mb = mask + b * SS;

    f32x4 oacc[2][4] = {};
    f32x4 lsum[2] = {};

    auto STAGE = [&](int buf, int tt) {
        int kt = (tt & 15) * 128;
        {
            int r8 = lane >> 3, c8 = lane & 7;
#pragma unroll
            for (int i = 0; i < 4; ++i) {
                int r = i * 32 + wid * 8 + r8;
                int cs = c8 ^ (r & 7);
                GL2LDS(Kp + (size_t)(b * SS + kt + r) * SD + h * 64 + cs * 8,
                       &Klds[buf][i * 32 + wid * 8][0]);
            }
        }
        {
            int r16 = lane >> 4, c16 = lane & 15;
#pragma unroll
            for (int i = 0; i < 4; ++i) {
                int r = i * 16 + wid * 4 + r16;
                int cs = (c16 & 8) | ((c16 & 7) ^ (r & 7));
                GL2LDS(VT + (size_t)(b * 1024 + h * 64 + r) * 2048 + kt + cs * 8,
                       &Vlds[buf][i * 16 + wid * 4][0]);
            }
        }
    };

    auto STEP = [&](int buf, int t) {
        int kt = t * 128;
        // mask additive terms, key = kt + cf*16 + 4*kg + j; fixed max folded (-8)
        f32x4 M[8];
#pragma unroll
        for (int cf = 0; cf < 8; ++cf) {
            int4 mi = *(const int4*)&Mb[kt + cf * 16 + 4 * kg];
            M[cf][0] = (float)mi.x * MSK - 8.0f;
            M[cf][1] = (float)mi.y * MSK - 8.0f;
            M[cf][2] = (float)mi.z * MSK - 8.0f;
            M[cf][3] = (float)mi.w * MSK - 8.0f;
        }
        // swapped QK^T: lane holds P[key=cf*16+4kg+j][q=qrow0+qh*16+cl]
        f32x4 sfr[8][2];
#pragma unroll
        for (int cf = 0; cf < 8; ++cf) {
            int r = cf * 16 + cl;
            bf16x8 kf0 = *(const bf16x8*)&Klds[buf][r][((0 + kg) ^ (r & 7)) * 8];
            bf16x8 kf1 = *(const bf16x8*)&Klds[buf][r][((4 + kg) ^ (r & 7)) * 8];
#pragma unroll
            for (int qh = 0; qh < 2; ++qh) {
                f32x4 s = {};
                s = __builtin_amdgcn_mfma_f32_16x16x32_bf16(kf0, qf[qh][0], s, 0, 0, 0);
                s = __builtin_amdgcn_mfma_f32_16x16x32_bf16(kf1, qf[qh][1], s, 0, 0, 0);
#pragma unroll
                for (int j = 0; j < 4; ++j)
                    s[j] = __builtin_amdgcn_exp2f(s[j] + M[cf][j]);
                sfr[cf][qh] = s;
                lsum[qh] += s;
            }
        }
        // PV: k-step ks covers cf {ks, ks+4}: key(8kg+e) = 16*(ks+4*(e>>2)) + 4kg + (e&3).
        // Lane's own sfr values ARE the A-fragment (no cross-lane, no LDS).
#pragma unroll
        for (int ks = 0; ks < 4; ++ks) {
            bf16x8 pa[2];
#pragma unroll
            for (int qh = 0; qh < 2; ++qh) {
                pa[qh][0] = (__bf16)sfr[ks][qh][0];
                pa[qh][1] = (__bf16)sfr[ks][qh][1];
                pa[qh][2] = (__bf16)sfr[ks][qh][2];
                pa[qh][3] = (__bf16)sfr[ks][qh][3];
                pa[qh][4] = (__bf16)sfr[ks + 4][qh][0];
                pa[qh][5] = (__bf16)sfr[ks + 4][qh][1];
                pa[qh][6] = (__bf16)sfr[ks + 4][qh][2];
                pa[qh][7] = (__bf16)sfr[ks + 4][qh][3];
            }
#pragma unroll
            for (int nf = 0; nf < 4; ++nf) {
                int d = nf * 16 + cl;
                int c16a = 2 * ks + (kg >> 1);            // chunk for cf=ks   (bit3=0)
                int c16b = 2 * (ks + 4) + (kg >> 1);      // chunk for cf=ks+4 (bit3=1)
                int cha = (c16a & 8) | ((c16a & 7) ^ (d & 7));
                int chb = (c16b & 8) | ((c16b & 7) ^ (d & 7));
                const char* vb = (const char*)&Vlds[buf][d][0];
                uint2v lo = *(const uint2v*)(vb + cha * 16 + (kg & 1) * 8);
                uint2v hi = *(const uint2v*)(vb + chb * 16 + (kg & 1) * 8);
                bf16x8 vf;
                *(uint2v*)&vf = lo;              // e0..3 <- keys 16*ks+4kg..+4
                *((uint2v*)&vf + 1) = hi;        // e4..7 <- keys 16*(ks+4)+4kg..+4
#pragma unroll
                for (int qh = 0; qh < 2; ++qh)
                    oacc[qh][nf] = __builtin_amdgcn_mfma_f32_16x16x32_bf16(
                        pa[qh], vf, oacc[qh][nf], 0, 0, 0);
            }
        }
    };

    STAGE(0, 0);
    __syncthreads();
    for (int t = 0; t < 16; ++t) {
        int cur = t & 1;
        STAGE(cur ^ 1, t + 1);                   // async loads for next tile
        STEP(cur, t);
        __syncthreads();                         // drains staging, orders buffers
    }

    // ---- epilogue: full l per q (reduce over kg lanes), redistribute, store.
    // oacc lane layout: O[q = qrow0 + qh*16 + 4kg+j][d = nf*16+cl]
    float lfull[2];
#pragma unroll
    for (int qh = 0; qh < 2; ++qh) {
        float l = (lsum[qh][0] + lsum[qh][1]) + (lsum[qh][2] + lsum[qh][3]);
        l += __shfl_xor(l, 16);
        l += __shfl_xor(l, 32);
        lfull[qh] = l;                            // valid in every lane for q=..+cl
    }
#pragma unroll
    for (int qh = 0; qh < 2; ++qh) {
#pragma unroll
        for (int j = 0; j < 4; ++j) {
            float inv = 1.0f / __shfl(lfull[qh], 4 * kg + j);
#pragma unroll
            for (int nf = 0; nf < 4; ++nf)
                O[(size_t)(b * SS + qrow0 + qh * 16 + 4 * kg + j) * SD + h * 64 + nf * 16 + cl] =
                    f2bf_(oacc[qh][nf][j] * inv);
        }
    }
}

// ---------------------------------------------------------------------------
extern "C" void kernel_launch(void* const* d_in, const int* in_sizes, int n_in,
                              void* d_out, int out_size, void* d_ws, size_t ws_size,
                              hipStream_t stream) {
    const float* q  = (const float*)d_in[0];
    const float* k  = (const float*)d_in[1];
    const float* v  = (const float*)d_in[2];
    const int*   mk = (const int*)d_in[3];
    const float* wq = (const float*)d_in[4];
    const float* bq = (const float*)d_in[5];
    const float* wk = (const float*)d_in[6];
    const float* bk = (const float*)d_in[7];
    const float* wv = (const float*)d_in[8];
    const float* bv = (const float*)d_in[9];
    const float* wo = (const float*)d_in[10];
    const float* bo = (const float*)d_in[11];
    float* out = (float*)d_out;

    char* ws = (char*)d_ws;
    unsigned short* WT  = (unsigned short*)ws;                   // 8 MB
    unsigned short* X   = (unsigned short*)(ws + 8388608);       // 16 MB (reused)
    unsigned short* Qh  = (unsigned short*)(ws + 25165824);
    unsigned short* Kh  = (unsigned short*)(ws + 41943040);
    unsigned short* VTr = (unsigned short*)(ws + 58720256);

    const int NACT = SB * SS * SD;  // 8388608
    const float QSCL = 0.125f * 1.4426950408889634f;  // 1/sqrt(64) * log2(e)

    transpose4<<<dim3(32, 32, 4), dim3(32, 8), 0, stream>>>(wq, wk, wv, wo, WT);

    dim3 gg(8, 64), gb(256);
    dim3 cg(2048), cb(256);

    f2b_kernel<<<cg, cb, 0, stream>>>(q, X, NACT);
    gemm_bt<0><<<gg, gb, 0, stream>>>(X, WT,               bq, Qh,  8192, 1024, 1024, QSCL);
    f2b_kernel<<<cg, cb, 0, stream>>>(k, X, NACT);
    gemm_bt<0><<<gg, gb, 0, stream>>>(X, WT + 1048576,     bk, Kh,  8192, 1024, 1024, 1.0f);
    f2b_kernel<<<cg, cb, 0, stream>>>(v, X, NACT);
    gemm_bt<1><<<gg, gb, 0, stream>>>(X, WT + 2 * 1048576, bv, VTr, 8192, 1024, 1024, 1.0f);

    attn_kernel<<<dim3(64, 16), dim3(256), 0, stream>>>(Qh, Kh, VTr, mk, X);

    gemm_bt<2><<<gg, gb, 0, stream>>>(X, WT + 3 * 1048576, bo, out, 8192, 1024, 1024, 1.0f);
}

// Round 10
// 250.853 us; speedup vs baseline: 2.9445x; 1.0557x over previous
//
#include <hip/hip_runtime.h>

// Problem constants: B=4, S=2048, D=1024, H=16, depth=64
#define SB 4
#define SS 2048
#define SD 1024
#define SH 16

typedef float f32x4 __attribute__((ext_vector_type(4)));
typedef __bf16 bf16x8 __attribute__((ext_vector_type(8)));
typedef short short4v __attribute__((ext_vector_type(4)));
typedef unsigned int uint2v __attribute__((ext_vector_type(2)));

__device__ __forceinline__ unsigned short f2bf_(float x) {
    unsigned u = __builtin_bit_cast(unsigned, x);
    unsigned r = u + 0x7FFFu + ((u >> 16) & 1u);
    return (unsigned short)(r >> 16);
}

#define GL2LDS(g, l) __builtin_amdgcn_global_load_lds( \
    (const __attribute__((address_space(1))) unsigned int*)(g), \
    (__attribute__((address_space(3))) unsigned int*)(l), 16, 0, 0)

// ---------------------------------------------------------------------------
// mask -> additive log2-domain term, fixed-max folded:  MA = mask*MSK - 8
// ---------------------------------------------------------------------------
__global__ __launch_bounds__(256) void maskprep(
        const int* __restrict__ mk, float* __restrict__ MA, int n) {
    int i = blockIdx.x * 256 + threadIdx.x;
    if (i < n)
        MA[i] = (float)mk[i] * (-1e9f * 1.4426950408889634f) - 8.0f;
}

// ---------------------------------------------------------------------------
// Transpose+convert 4 weight matrices fp32[1024,1024] -> bf16 [1024,1024]^T
// ---------------------------------------------------------------------------
__global__ __launch_bounds__(256) void transpose4(
        const float* __restrict__ w0, const float* __restrict__ w1,
        const float* __restrict__ w2, const float* __restrict__ w3,
        unsigned short* __restrict__ out) {
    __shared__ unsigned short tile[32][33];
    int zz = blockIdx.z;
    const float* src = (zz == 0) ? w0 : (zz == 1) ? w1 : (zz == 2) ? w2 : w3;
    unsigned short* dst = out + (size_t)zz * 1024 * 1024;
    int x = blockIdx.x * 32 + threadIdx.x;
    int y0 = blockIdx.y * 32;
    for (int j = threadIdx.y; j < 32; j += 8)
        tile[j][threadIdx.x] = f2bf_(src[(size_t)(y0 + j) * 1024 + x]);
    __syncthreads();
    int ox = y0 + threadIdx.x;
    int oy0 = blockIdx.x * 32;
    for (int j = threadIdx.y; j < 32; j += 8)
        dst[(size_t)(oy0 + j) * 1024 + ox] = tile[threadIdx.x][j];
}

// ---------------------------------------------------------------------------
// GEMM: C[M,N] = (A[M,K] @ BT[N,K]^T + bias[N]) * oscale   (fp32 accum)
// AFP32=1: A is fp32, staged raw to LDS (swizzled), converted at frag load.
// AFP32=0: A is bf16 (m97-style staging).
// Double-buffered LDS: STAGE(t+1) issued before compute(t), 1 barrier/iter.
// STORE_MODE 0: bf16 row-major; 1: V^T per-head store; 2: fp32 row-major
// ---------------------------------------------------------------------------
template <int STORE_MODE, int AFP32>
__global__ __launch_bounds__(256) void gemm_bt(
        const void* __restrict__ Av, const unsigned short* __restrict__ BT,
        const float* __restrict__ bias, void* __restrict__ Cv,
        int M, int N, int K, float oscale) {
    __shared__ alignas(16) char AsmRaw[AFP32 ? 2 * 128 * 32 * 4 : 2 * 128 * 32 * 2];
    __shared__ alignas(16) unsigned short Bsm[2][128][32];
    auto Asmf = (float(*)[128][32])AsmRaw;
    auto Asmb = (unsigned short(*)[128][32])AsmRaw;
    const float* Af = (const float*)Av;
    const unsigned short* Ab = (const unsigned short*)Av;

    const int m0 = blockIdx.y * 128, n0 = blockIdx.x * 128;
    const int tid = threadIdx.x;
    const int lane = tid & 63, wid = tid >> 6;
    const int wr = wid >> 1, wc = wid & 1;
    const int lr = lane >> 2;            // bf16 staging: row within 16-row chunk
    const int lco = (lane & 3) * 8;      // bf16 staging: elem offset (16B)
    const int cl = lane & 15, kg = lane >> 4;

    f32x4 acc[4][4] = {};

    auto STAGE = [&](int buf, int k0) {
        if (AFP32) {
#pragma unroll
            for (int i = 0; i < 4; ++i) {
                int base = i * 32 + wid * 8;
                int row = base + (lane >> 3);
                int cs = (lane & 7) ^ (row & 7);     // source chunk pre-swizzle
                GL2LDS(Af + (size_t)(m0 + row) * K + k0 + cs * 4, &Asmf[buf][base][0]);
            }
        } else {
#pragma unroll
            for (int i = 0; i < 2; ++i) {
                int base = (i * 4 + wid) * 16;
                GL2LDS(Ab + (size_t)(m0 + base + lr) * K + k0 + lco, &Asmb[buf][base][0]);
            }
        }
#pragma unroll
        for (int i = 0; i < 2; ++i) {
            int base = (i * 4 + wid) * 16;
            GL2LDS(BT + (size_t)(n0 + base + lr) * K + k0 + lco, &Bsm[buf][base][0]);
        }
    };

    STAGE(0, 0);
    __syncthreads();

    for (int k0 = 0; k0 < K; k0 += 32) {
        int cur = (k0 >> 5) & 1;
        if (k0 + 32 < K) STAGE(cur ^ 1, k0 + 32);   // async prefetch next tile

        bf16x8 af[4], bfv[4];
        if (AFP32) {
#pragma unroll
            for (int mi = 0; mi < 4; ++mi) {
                int r = wr * 64 + mi * 16 + cl;
                const float* Ar = &Asmf[cur][r][0];
                f32x4 a0 = *(const f32x4*)(Ar + ((2 * kg) ^ (r & 7)) * 4);
                f32x4 a1 = *(const f32x4*)(Ar + ((2 * kg + 1) ^ (r & 7)) * 4);
#pragma unroll
                for (int e = 0; e < 4; ++e) {
                    af[mi][e] = (__bf16)a0[e];
                    af[mi][4 + e] = (__bf16)a1[e];
                }
            }
        } else {
#pragma unroll
            for (int mi = 0; mi < 4; ++mi)
                af[mi] = *(const bf16x8*)&Asmb[cur][wr * 64 + mi * 16 + cl][kg * 8];
        }
#pragma unroll
        for (int ni = 0; ni < 4; ++ni)
            bfv[ni] = *(const bf16x8*)&Bsm[cur][wc * 64 + ni * 16 + cl][kg * 8];
#pragma unroll
        for (int mi = 0; mi < 4; ++mi)
#pragma unroll
            for (int ni = 0; ni < 4; ++ni)
                acc[mi][ni] = __builtin_amdgcn_mfma_f32_16x16x32_bf16(
                    af[mi], bfv[ni], acc[mi][ni], 0, 0, 0);
        __syncthreads();   // staging of next tile complete; reads of cur done
    }

    const int rl = (lane >> 4) * 4;
#pragma unroll
    for (int mi = 0; mi < 4; ++mi) {
#pragma unroll
        for (int ni = 0; ni < 4; ++ni) {
            int row = m0 + wr * 64 + mi * 16 + rl;
            int col = n0 + wc * 64 + ni * 16 + cl;
            float bv = bias[col];
            f32x4 v = acc[mi][ni];
            if (STORE_MODE == 0) {
                unsigned short* C = (unsigned short*)Cv;
#pragma unroll
                for (int j = 0; j < 4; ++j)
                    C[(size_t)(row + j) * N + col] = f2bf_((v[j] + bv) * oscale);
            } else if (STORE_MODE == 1) {
                unsigned short* C = (unsigned short*)Cv;
                int bb = row >> 11, s = row & 2047;
                short4v pk;
#pragma unroll
                for (int j = 0; j < 4; ++j)
                    pk[j] = (short)f2bf_(v[j] + bv);
                *(short4v*)&C[((size_t)(bb * 1024 + col)) * 2048 + s] = pk;
            } else {
                float* C = (float*)Cv;
#pragma unroll
                for (int j = 0; j < 4; ++j)
                    C[(size_t)(row + j) * N + col] = v[j] + bv;
            }
        }
    }
}

// ---------------------------------------------------------------------------
// Flash attention v3: swapped QK^T (P register-resident), fixed-max softmax,
// 32 q-rows per wave, KBLK=128 LDS-staged K/V (double-buffered, swizzled).
// Qp: [B*S,1024] bf16 PRE-SCALED by 0.125*log2e. Kp: [B*S,1024] bf16.
// VT: [B*1024,2048] bf16 (row=b*1024+h*64+d, col=s). MA: [B,S] fp32
// (mask*MSK-8). O: [B*S,1024] bf16.
// ---------------------------------------------------------------------------
__global__ __launch_bounds__(256, 2) void attn_kernel(
        const unsigned short* __restrict__ Qp, const unsigned short* __restrict__ Kp,
        const unsigned short* __restrict__ VT, const float* __restrict__ MA,
        unsigned short* __restrict__ O) {
    __shared__ alignas(16) unsigned short Klds[2][128][64];
    __shared__ alignas(16) unsigned short Vlds[2][64][128];
    const int lane = threadIdx.x & 63, wid = threadIdx.x >> 6;
    const int bh = blockIdx.x;
    const int b = bh >> 4, h = bh & 15;
    const int qt = blockIdx.y;
    const int qrow0 = qt * 128 + wid * 32;
    const int cl = lane & 15, kg = lane >> 4;

    // Q as B-operand: frag [qh][kh]: col=cl -> q=qrow0+qh*16+cl, k=kh*32+kg*8
    bf16x8 qf[2][2];
#pragma unroll
    for (int qh = 0; qh < 2; ++qh)
#pragma unroll
        for (int kh = 0; kh < 2; ++kh)
            qf[qh][kh] = *(const bf16x8*)&Qp[(size_t)(b * SS + qrow0 + qh * 16 + cl) * SD
                                            + h * 64 + kh * 32 + kg * 8];

    const float* MAb = MA + b * SS;

    f32x4 oacc[2][4] = {};
    f32x4 lsum[2] = {};

    auto STAGE = [&](int buf, int tt) {
        int kt = (tt & 15) * 128;
        {
            int r8 = lane >> 3, c8 = lane & 7;
#pragma unroll
            for (int i = 0; i < 4; ++i) {
                int r = i * 32 + wid * 8 + r8;
                int cs = c8 ^ (r & 7);
                GL2LDS(Kp + (size_t)(b * SS + kt + r) * SD + h * 64 + cs * 8,
                       &Klds[buf][i * 32 + wid * 8][0]);
            }
        }
        {
            int r16 = lane >> 4, c16 = lane & 15;
#pragma unroll
            for (int i = 0; i < 4; ++i) {
                int r = i * 16 + wid * 4 + r16;
                int cs = (c16 & 8) | ((c16 & 7) ^ (r & 7));
                GL2LDS(VT + (size_t)(b * 1024 + h * 64 + r) * 2048 + kt + cs * 8,
                       &Vlds[buf][i * 16 + wid * 4][0]);
            }
        }
    };

    auto STEP = [&](int buf, int t) {
        int kt = t * 128;
        f32x4 M[8];
#pragma unroll
        for (int cf = 0; cf < 8; ++cf)
            M[cf] = *(const f32x4*)&MAb[kt + cf * 16 + 4 * kg];
        // swapped QK^T: lane holds P[key=cf*16+4kg+j][q=qrow0+qh*16+cl]
        f32x4 sfr[8][2];
#pragma unroll
        for (int cf = 0; cf < 8; ++cf) {
            int r = cf * 16 + cl;
            bf16x8 kf0 = *(const bf16x8*)&Klds[buf][r][((0 + kg) ^ (r & 7)) * 8];
            bf16x8 kf1 = *(const bf16x8*)&Klds[buf][r][((4 + kg) ^ (r & 7)) * 8];
#pragma unroll
            for (int qh = 0; qh < 2; ++qh) {
                f32x4 s = {};
                s = __builtin_amdgcn_mfma_f32_16x16x32_bf16(kf0, qf[qh][0], s, 0, 0, 0);
                s = __builtin_amdgcn_mfma_f32_16x16x32_bf16(kf1, qf[qh][1], s, 0, 0, 0);
#pragma unroll
                for (int j = 0; j < 4; ++j)
                    s[j] = __builtin_amdgcn_exp2f(s[j] + M[cf][j]);
                sfr[cf][qh] = s;
                lsum[qh] += s;
            }
        }
        // PV: lane's sfr values ARE the A-fragment under
        // key(8kg+e) = 16*(ks+4*(e>>2)) + 4kg + (e&3); V B-frag via 2x b64.
#pragma unroll
        for (int ks = 0; ks < 4; ++ks) {
            bf16x8 pa[2];
#pragma unroll
            for (int qh = 0; qh < 2; ++qh) {
                pa[qh][0] = (__bf16)sfr[ks][qh][0];
                pa[qh][1] = (__bf16)sfr[ks][qh][1];
                pa[qh][2] = (__bf16)sfr[ks][qh][2];
                pa[qh][3] = (__bf16)sfr[ks][qh][3];
                pa[qh][4] = (__bf16)sfr[ks + 4][qh][0];
                pa[qh][5] = (__bf16)sfr[ks + 4][qh][1];
                pa[qh][6] = (__bf16)sfr[ks + 4][qh][2];
                pa[qh][7] = (__bf16)sfr[ks + 4][qh][3];
            }
#pragma unroll
            for (int nf = 0; nf < 4; ++nf) {
                int d = nf * 16 + cl;
                int c16a = 2 * ks + (kg >> 1);
                int c16b = 2 * (ks + 4) + (kg >> 1);
                int cha = (c16a & 8) | ((c16a & 7) ^ (d & 7));
                int chb = (c16b & 8) | ((c16b & 7) ^ (d & 7));
                const char* vb = (const char*)&Vlds[buf][d][0];
                uint2v lo = *(const uint2v*)(vb + cha * 16 + (kg & 1) * 8);
                uint2v hi = *(const uint2v*)(vb + chb * 16 + (kg & 1) * 8);
                bf16x8 vf;
                *(uint2v*)&vf = lo;
                *((uint2v*)&vf + 1) = hi;
#pragma unroll
                for (int qh = 0; qh < 2; ++qh)
                    oacc[qh][nf] = __builtin_amdgcn_mfma_f32_16x16x32_bf16(
                        pa[qh], vf, oacc[qh][nf], 0, 0, 0);
            }
        }
    };

    STAGE(0, 0);
    __syncthreads();
    for (int t = 0; t < 16; ++t) {
        int cur = t & 1;
        STAGE(cur ^ 1, t + 1);
        STEP(cur, t);
        __syncthreads();
    }

    // ---- epilogue: reduce l over kg lanes, redistribute, store
    float lfull[2];
#pragma unroll
    for (int qh = 0; qh < 2; ++qh) {
        float l = (lsum[qh][0] + lsum[qh][1]) + (lsum[qh][2] + lsum[qh][3]);
        l += __shfl_xor(l, 16);
        l += __shfl_xor(l, 32);
        lfull[qh] = l;
    }
#pragma unroll
    for (int qh = 0; qh < 2; ++qh) {
#pragma unroll
        for (int j = 0; j < 4; ++j) {
            float inv = 1.0f / __shfl(lfull[qh], 4 * kg + j);
#pragma unroll
            for (int nf = 0; nf < 4; ++nf)
                O[(size_t)(b * SS + qrow0 + qh * 16 + 4 * kg + j) * SD + h * 64 + nf * 16 + cl] =
                    f2bf_(oacc[qh][nf][j] * inv);
        }
    }
}

// ---------------------------------------------------------------------------
extern "C" void kernel_launch(void* const* d_in, const int* in_sizes, int n_in,
                              void* d_out, int out_size, void* d_ws, size_t ws_size,
                              hipStream_t stream) {
    const float* q  = (const float*)d_in[0];
    const float* k  = (const float*)d_in[1];
    const float* v  = (const float*)d_in[2];
    const int*   mk = (const int*)d_in[3];
    const float* wq = (const float*)d_in[4];
    const float* bq = (const float*)d_in[5];
    const float* wk = (const float*)d_in[6];
    const float* bk = (const float*)d_in[7];
    const float* wv = (const float*)d_in[8];
    const float* bv = (const float*)d_in[9];
    const float* wo = (const float*)d_in[10];
    const float* bo = (const float*)d_in[11];
    float* out = (float*)d_out;

    char* ws = (char*)d_ws;
    unsigned short* WT  = (unsigned short*)ws;                   // 8 MB
    unsigned short* X   = (unsigned short*)(ws + 8388608);       // attn out (bf16)
    unsigned short* Qh  = (unsigned short*)(ws + 25165824);
    unsigned short* Kh  = (unsigned short*)(ws + 41943040);
    unsigned short* VTr = (unsigned short*)(ws + 58720256);
    float*          MAf = (float*)(ws + 75497472);               // 32 KB

    const float QSCL = 0.125f * 1.4426950408889634f;  // 1/sqrt(64) * log2(e)

    transpose4<<<dim3(32, 32, 4), dim3(32, 8), 0, stream>>>(wq, wk, wv, wo, WT);
    maskprep<<<dim3(32), dim3(256), 0, stream>>>(mk, MAf, SB * SS);

    dim3 gg(8, 64), gb(256);

    gemm_bt<0, 1><<<gg, gb, 0, stream>>>(q, WT,               bq, Qh,  8192, 1024, 1024, QSCL);
    gemm_bt<0, 1><<<gg, gb, 0, stream>>>(k, WT + 1048576,     bk, Kh,  8192, 1024, 1024, 1.0f);
    gemm_bt<1, 1><<<gg, gb, 0, stream>>>(v, WT + 2 * 1048576, bv, VTr, 8192, 1024, 1024, 1.0f);

    attn_kernel<<<dim3(64, 16), dim3(256), 0, stream>>>(Qh, Kh, VTr, MAf, X);

    gemm_bt<2, 0><<<gg, gb, 0, stream>>>(X, WT + 3 * 1048576, bo, out, 8192, 1024, 1024, 1.0f);
}

// Round 11
// 221.160 us; speedup vs baseline: 3.3398x; 1.1343x over previous
//
#include <hip/hip_runtime.h>

// Problem constants: B=4, S=2048, D=1024, H=16, depth=64
#define SB 4
#define SS 2048
#define SD 1024
#define SH 16

typedef float f32x4 __attribute__((ext_vector_type(4)));
typedef __bf16 bf16x8 __attribute__((ext_vector_type(8)));
typedef short short4v __attribute__((ext_vector_type(4)));
typedef unsigned int uint2v __attribute__((ext_vector_type(2)));

__device__ __forceinline__ unsigned short f2bf_(float x) {
    unsigned u = __builtin_bit_cast(unsigned, x);
    unsigned r = u + 0x7FFFu + ((u >> 16) & 1u);
    return (unsigned short)(r >> 16);
}

#define GL2LDS(g, l) __builtin_amdgcn_global_load_lds( \
    (const __attribute__((address_space(1))) unsigned int*)(g), \
    (__attribute__((address_space(3))) unsigned int*)(l), 16, 0, 0)

// ---------------------------------------------------------------------------
// mask -> additive log2-domain term, fixed-max folded:  MA = mask*MSK - 8
// ---------------------------------------------------------------------------
__global__ __launch_bounds__(256) void maskprep(
        const int* __restrict__ mk, float* __restrict__ MA, int n) {
    int i = blockIdx.x * 256 + threadIdx.x;
    if (i < n)
        MA[i] = (float)mk[i] * (-1e9f * 1.4426950408889634f) - 8.0f;
}

// ---------------------------------------------------------------------------
// Transpose+convert 4 weight matrices fp32[1024,1024] -> bf16 [1024,1024]^T
// ---------------------------------------------------------------------------
__global__ __launch_bounds__(256) void transpose4(
        const float* __restrict__ w0, const float* __restrict__ w1,
        const float* __restrict__ w2, const float* __restrict__ w3,
        unsigned short* __restrict__ out) {
    __shared__ unsigned short tile[32][33];
    int zz = blockIdx.z;
    const float* src = (zz == 0) ? w0 : (zz == 1) ? w1 : (zz == 2) ? w2 : w3;
    unsigned short* dst = out + (size_t)zz * 1024 * 1024;
    int x = blockIdx.x * 32 + threadIdx.x;
    int y0 = blockIdx.y * 32;
    for (int j = threadIdx.y; j < 32; j += 8)
        tile[j][threadIdx.x] = f2bf_(src[(size_t)(y0 + j) * 1024 + x]);
    __syncthreads();
    int ox = y0 + threadIdx.x;
    int oy0 = blockIdx.x * 32;
    for (int j = threadIdx.y; j < 32; j += 8)
        dst[(size_t)(oy0 + j) * 1024 + ox] = tile[threadIdx.x][j];
}

// ---------------------------------------------------------------------------
// GEMM: C[M,N] = (A[M,K] @ BT[N,K]^T + bias[N]) * oscale   (fp32 accum)
// Grid: x = M-tile, y = N-tile  => blocks sharing an A-panel have ids
// m + (M/128)*n; id%8 == m%8 -> same XCD -> A-panel L2-resident (fetch once).
// AFP32=1: A is fp32, staged raw to LDS (swizzled), converted at frag load.
// Double-buffered LDS: STAGE(t+1) issued before compute(t), 1 barrier/iter.
// STORE_MODE 0: bf16 row-major; 1: V^T per-head store; 2: fp32 row-major
// ---------------------------------------------------------------------------
template <int STORE_MODE, int AFP32>
__global__ __launch_bounds__(256) void gemm_bt(
        const void* __restrict__ Av, const unsigned short* __restrict__ BT,
        const float* __restrict__ bias, void* __restrict__ Cv,
        int M, int N, int K, float oscale) {
    __shared__ alignas(16) char AsmRaw[AFP32 ? 2 * 128 * 32 * 4 : 2 * 128 * 32 * 2];
    __shared__ alignas(16) unsigned short Bsm[2][128][32];
    auto Asmf = (float(*)[128][32])AsmRaw;
    auto Asmb = (unsigned short(*)[128][32])AsmRaw;
    const float* Af = (const float*)Av;
    const unsigned short* Ab = (const unsigned short*)Av;

    const int m0 = blockIdx.x * 128, n0 = blockIdx.y * 128;
    const int tid = threadIdx.x;
    const int lane = tid & 63, wid = tid >> 6;
    const int wr = wid >> 1, wc = wid & 1;
    const int lr = lane >> 2;            // bf16 staging: row within 16-row chunk
    const int lco = (lane & 3) * 8;      // bf16 staging: elem offset (16B)
    const int cl = lane & 15, kg = lane >> 4;

    f32x4 acc[4][4] = {};

    auto STAGE = [&](int buf, int k0) {
        if (AFP32) {
#pragma unroll
            for (int i = 0; i < 4; ++i) {
                int base = i * 32 + wid * 8;
                int row = base + (lane >> 3);
                int cs = (lane & 7) ^ (row & 7);     // source chunk pre-swizzle
                GL2LDS(Af + (size_t)(m0 + row) * K + k0 + cs * 4, &Asmf[buf][base][0]);
            }
        } else {
#pragma unroll
            for (int i = 0; i < 2; ++i) {
                int base = (i * 4 + wid) * 16;
                GL2LDS(Ab + (size_t)(m0 + base + lr) * K + k0 + lco, &Asmb[buf][base][0]);
            }
        }
#pragma unroll
        for (int i = 0; i < 2; ++i) {
            int base = (i * 4 + wid) * 16;
            GL2LDS(BT + (size_t)(n0 + base + lr) * K + k0 + lco, &Bsm[buf][base][0]);
        }
    };

    STAGE(0, 0);
    __syncthreads();

    for (int k0 = 0; k0 < K; k0 += 32) {
        int cur = (k0 >> 5) & 1;
        if (k0 + 32 < K) STAGE(cur ^ 1, k0 + 32);   // async prefetch next tile

        bf16x8 af[4], bfv[4];
        if (AFP32) {
#pragma unroll
            for (int mi = 0; mi < 4; ++mi) {
                int r = wr * 64 + mi * 16 + cl;
                const float* Ar = &Asmf[cur][r][0];
                f32x4 a0 = *(const f32x4*)(Ar + ((2 * kg) ^ (r & 7)) * 4);
                f32x4 a1 = *(const f32x4*)(Ar + ((2 * kg + 1) ^ (r & 7)) * 4);
#pragma unroll
                for (int e = 0; e < 4; ++e) {
                    af[mi][e] = (__bf16)a0[e];
                    af[mi][4 + e] = (__bf16)a1[e];
                }
            }
        } else {
#pragma unroll
            for (int mi = 0; mi < 4; ++mi)
                af[mi] = *(const bf16x8*)&Asmb[cur][wr * 64 + mi * 16 + cl][kg * 8];
        }
#pragma unroll
        for (int ni = 0; ni < 4; ++ni)
            bfv[ni] = *(const bf16x8*)&Bsm[cur][wc * 64 + ni * 16 + cl][kg * 8];
#pragma unroll
        for (int mi = 0; mi < 4; ++mi)
#pragma unroll
            for (int ni = 0; ni < 4; ++ni)
                acc[mi][ni] = __builtin_amdgcn_mfma_f32_16x16x32_bf16(
                    af[mi], bfv[ni], acc[mi][ni], 0, 0, 0);
        __syncthreads();   // staging of next tile complete; reads of cur done
    }

    const int rl = (lane >> 4) * 4;
#pragma unroll
    for (int mi = 0; mi < 4; ++mi) {
#pragma unroll
        for (int ni = 0; ni < 4; ++ni) {
            int row = m0 + wr * 64 + mi * 16 + rl;
            int col = n0 + wc * 64 + ni * 16 + cl;
            float bv = bias[col];
            f32x4 v = acc[mi][ni];
            if (STORE_MODE == 0) {
                unsigned short* C = (unsigned short*)Cv;
#pragma unroll
                for (int j = 0; j < 4; ++j)
                    C[(size_t)(row + j) * N + col] = f2bf_((v[j] + bv) * oscale);
            } else if (STORE_MODE == 1) {
                unsigned short* C = (unsigned short*)Cv;
                int bb = row >> 11, s = row & 2047;
                short4v pk;
#pragma unroll
                for (int j = 0; j < 4; ++j)
                    pk[j] = (short)f2bf_(v[j] + bv);
                *(short4v*)&C[((size_t)(bb * 1024 + col)) * 2048 + s] = pk;
            } else {
                float* C = (float*)Cv;
#pragma unroll
                for (int j = 0; j < 4; ++j)
                    C[(size_t)(row + j) * N + col] = v[j] + bv;
            }
        }
    }
}

// ---------------------------------------------------------------------------
// Flash attention v3: swapped QK^T (P register-resident), fixed-max softmax,
// 32 q-rows per wave, KBLK=128 LDS-staged K/V (double-buffered, swizzled).
// Qp: [B*S,1024] bf16 PRE-SCALED by 0.125*log2e. Kp: [B*S,1024] bf16.
// VT: [B*1024,2048] bf16 (row=b*1024+h*64+d, col=s). MA: [B,S] fp32
// (mask*MSK-8). O: [B*S,1024] bf16.
// ---------------------------------------------------------------------------
__global__ __launch_bounds__(256, 2) void attn_kernel(
        const unsigned short* __restrict__ Qp, const unsigned short* __restrict__ Kp,
        const unsigned short* __restrict__ VT, const float* __restrict__ MA,
        unsigned short* __restrict__ O) {
    __shared__ alignas(16) unsigned short Klds[2][128][64];
    __shared__ alignas(16) unsigned short Vlds[2][64][128];
    const int lane = threadIdx.x & 63, wid = threadIdx.x >> 6;
    const int bh = blockIdx.x;
    const int b = bh >> 4, h = bh & 15;
    const int qt = blockIdx.y;
    const int qrow0 = qt * 128 + wid * 32;
    const int cl = lane & 15, kg = lane >> 4;

    // Q as B-operand: frag [qh][kh]: col=cl -> q=qrow0+qh*16+cl, k=kh*32+kg*8
    bf16x8 qf[2][2];
#pragma unroll
    for (int qh = 0; qh < 2; ++qh)
#pragma unroll
        for (int kh = 0; kh < 2; ++kh)
            qf[qh][kh] = *(const bf16x8*)&Qp[(size_t)(b * SS + qrow0 + qh * 16 + cl) * SD
                                            + h * 64 + kh * 32 + kg * 8];

    const float* MAb = MA + b * SS;

    f32x4 oacc[2][4] = {};
    f32x4 lsum[2] = {};

    auto STAGE = [&](int buf, int tt) {
        int kt = (tt & 15) * 128;
        {
            int r8 = lane >> 3, c8 = lane & 7;
#pragma unroll
            for (int i = 0; i < 4; ++i) {
                int r = i * 32 + wid * 8 + r8;
                int cs = c8 ^ (r & 7);
                GL2LDS(Kp + (size_t)(b * SS + kt + r) * SD + h * 64 + cs * 8,
                       &Klds[buf][i * 32 + wid * 8][0]);
            }
        }
        {
            int r16 = lane >> 4, c16 = lane & 15;
#pragma unroll
            for (int i = 0; i < 4; ++i) {
                int r = i * 16 + wid * 4 + r16;
                int cs = (c16 & 8) | ((c16 & 7) ^ (r & 7));
                GL2LDS(VT + (size_t)(b * 1024 + h * 64 + r) * 2048 + kt + cs * 8,
                       &Vlds[buf][i * 16 + wid * 4][0]);
            }
        }
    };

    auto STEP = [&](int buf, int t) {
        int kt = t * 128;
        f32x4 M[8];
#pragma unroll
        for (int cf = 0; cf < 8; ++cf)
            M[cf] = *(const f32x4*)&MAb[kt + cf * 16 + 4 * kg];
        // swapped QK^T: lane holds P[key=cf*16+4kg+j][q=qrow0+qh*16+cl]
        f32x4 sfr[8][2];
#pragma unroll
        for (int cf = 0; cf < 8; ++cf) {
            int r = cf * 16 + cl;
            bf16x8 kf0 = *(const bf16x8*)&Klds[buf][r][((0 + kg) ^ (r & 7)) * 8];
            bf16x8 kf1 = *(const bf16x8*)&Klds[buf][r][((4 + kg) ^ (r & 7)) * 8];
#pragma unroll
            for (int qh = 0; qh < 2; ++qh) {
                f32x4 s = {};
                s = __builtin_amdgcn_mfma_f32_16x16x32_bf16(kf0, qf[qh][0], s, 0, 0, 0);
                s = __builtin_amdgcn_mfma_f32_16x16x32_bf16(kf1, qf[qh][1], s, 0, 0, 0);
#pragma unroll
                for (int j = 0; j < 4; ++j)
                    s[j] = __builtin_amdgcn_exp2f(s[j] + M[cf][j]);
                sfr[cf][qh] = s;
                lsum[qh] += s;
            }
        }
        // PV: lane's sfr values ARE the A-fragment under
        // key(8kg+e) = 16*(ks+4*(e>>2)) + 4kg + (e&3); V B-frag via 2x b64.
#pragma unroll
        for (int ks = 0; ks < 4; ++ks) {
            bf16x8 pa[2];
#pragma unroll
            for (int qh = 0; qh < 2; ++qh) {
                pa[qh][0] = (__bf16)sfr[ks][qh][0];
                pa[qh][1] = (__bf16)sfr[ks][qh][1];
                pa[qh][2] = (__bf16)sfr[ks][qh][2];
                pa[qh][3] = (__bf16)sfr[ks][qh][3];
                pa[qh][4] = (__bf16)sfr[ks + 4][qh][0];
                pa[qh][5] = (__bf16)sfr[ks + 4][qh][1];
                pa[qh][6] = (__bf16)sfr[ks + 4][qh][2];
                pa[qh][7] = (__bf16)sfr[ks + 4][qh][3];
            }
#pragma unroll
            for (int nf = 0; nf < 4; ++nf) {
                int d = nf * 16 + cl;
                int c16a = 2 * ks + (kg >> 1);
                int c16b = 2 * (ks + 4) + (kg >> 1);
                int cha = (c16a & 8) | ((c16a & 7) ^ (d & 7));
                int chb = (c16b & 8) | ((c16b & 7) ^ (d & 7));
                const char* vb = (const char*)&Vlds[buf][d][0];
                uint2v lo = *(const uint2v*)(vb + cha * 16 + (kg & 1) * 8);
                uint2v hi = *(const uint2v*)(vb + chb * 16 + (kg & 1) * 8);
                bf16x8 vf;
                *(uint2v*)&vf = lo;
                *((uint2v*)&vf + 1) = hi;
#pragma unroll
                for (int qh = 0; qh < 2; ++qh)
                    oacc[qh][nf] = __builtin_amdgcn_mfma_f32_16x16x32_bf16(
                        pa[qh], vf, oacc[qh][nf], 0, 0, 0);
            }
        }
    };

    STAGE(0, 0);
    __syncthreads();
    for (int t = 0; t < 16; ++t) {
        int cur = t & 1;
        STAGE(cur ^ 1, t + 1);
        STEP(cur, t);
        __syncthreads();
    }

    // ---- epilogue: reduce l over kg lanes, redistribute, store
    float lfull[2];
#pragma unroll
    for (int qh = 0; qh < 2; ++qh) {
        float l = (lsum[qh][0] + lsum[qh][1]) + (lsum[qh][2] + lsum[qh][3]);
        l += __shfl_xor(l, 16);
        l += __shfl_xor(l, 32);
        lfull[qh] = l;
    }
#pragma unroll
    for (int qh = 0; qh < 2; ++qh) {
#pragma unroll
        for (int j = 0; j < 4; ++j) {
            float inv = 1.0f / __shfl(lfull[qh], 4 * kg + j);
#pragma unroll
            for (int nf = 0; nf < 4; ++nf)
                O[(size_t)(b * SS + qrow0 + qh * 16 + 4 * kg + j) * SD + h * 64 + nf * 16 + cl] =
                    f2bf_(oacc[qh][nf][j] * inv);
        }
    }
}

// ---------------------------------------------------------------------------
extern "C" void kernel_launch(void* const* d_in, const int* in_sizes, int n_in,
                              void* d_out, int out_size, void* d_ws, size_t ws_size,
                              hipStream_t stream) {
    const float* q  = (const float*)d_in[0];
    const float* k  = (const float*)d_in[1];
    const float* v  = (const float*)d_in[2];
    const int*   mk = (const int*)d_in[3];
    const float* wq = (const float*)d_in[4];
    const float* bq = (const float*)d_in[5];
    const float* wk = (const float*)d_in[6];
    const float* bk = (const float*)d_in[7];
    const float* wv = (const float*)d_in[8];
    const float* bv = (const float*)d_in[9];
    const float* wo = (const float*)d_in[10];
    const float* bo = (const float*)d_in[11];
    float* out = (float*)d_out;

    char* ws = (char*)d_ws;
    unsigned short* WT  = (unsigned short*)ws;                   // 8 MB
    unsigned short* X   = (unsigned short*)(ws + 8388608);       // attn out (bf16)
    unsigned short* Qh  = (unsigned short*)(ws + 25165824);
    unsigned short* Kh  = (unsigned short*)(ws + 41943040);
    unsigned short* VTr = (unsigned short*)(ws + 58720256);
    float*          MAf = (float*)(ws + 75497472);               // 32 KB

    const float QSCL = 0.125f * 1.4426950408889634f;  // 1/sqrt(64) * log2(e)

    transpose4<<<dim3(32, 32, 4), dim3(32, 8), 0, stream>>>(wq, wk, wv, wo, WT);
    maskprep<<<dim3(32), dim3(256), 0, stream>>>(mk, MAf, SB * SS);

    dim3 gg(64, 8), gb(256);   // x = M-tile, y = N-tile (A-panel XCD locality)

    gemm_bt<0, 1><<<gg, gb, 0, stream>>>(q, WT,               bq, Qh,  8192, 1024, 1024, QSCL);
    gemm_bt<0, 1><<<gg, gb, 0, stream>>>(k, WT + 1048576,     bk, Kh,  8192, 1024, 1024, 1.0f);
    gemm_bt<1, 1><<<gg, gb, 0, stream>>>(v, WT + 2 * 1048576, bv, VTr, 8192, 1024, 1024, 1.0f);

    attn_kernel<<<dim3(64, 16), dim3(256), 0, stream>>>(Qh, Kh, VTr, MAf, X);

    gemm_bt<2, 0><<<gg, gb, 0, stream>>>(X, WT + 3 * 1048576, bo, out, 8192, 1024, 1024, 1.0f);
}